// Round 5
// baseline (586.757 us; speedup 1.0000x reference)
//
#include <hip/hip_runtime.h>
#include <hip/hip_bf16.h>

#define N0_  320000
#define N1_  80000
#define N2_  16000
#define INC_ 128
#define HID_ 64
#define H1_  4
#define C1_  256   // H1*HID
#define OUT_ 48
#define OUTP_ 64   // padded layer-2 feature stride
#define NEG_ 0.2f

typedef __attribute__((ext_vector_type(8))) short bfrag8;   // 8 bf16 (4 VGPRs)
typedef __attribute__((ext_vector_type(4))) float ffrag4;   // 4 fp32 acc

__device__ __forceinline__ float bf2f(unsigned short u){
  unsigned int v = ((unsigned int)u) << 16;
  return __uint_as_float(v);
}
__device__ __forceinline__ unsigned short f2bf(float f){
  unsigned int u = __float_as_uint(f);
  u += 0x7FFFu + ((u >> 16) & 1u);   // round-to-nearest-even
  return (unsigned short)(u >> 16);
}
__device__ __forceinline__ void unpack2(unsigned int u, float& lo, float& hi){
  lo = __uint_as_float(u << 16);
  hi = __uint_as_float(u & 0xffff0000u);
}

// ---- all 4 weight transposes in one kernel (f32 [K][N] -> bf16 [N][K]) ----
__global__ void transpose_all(const float* __restrict__ Wl1, const float* __restrict__ Wr1,
                              const float* __restrict__ Wl2, const float* __restrict__ Wr2,
                              unsigned short* __restrict__ Wt1l, unsigned short* __restrict__ Wt1r,
                              unsigned short* __restrict__ Wt2l, unsigned short* __restrict__ Wt2r){
  int idx = blockIdx.x*256 + threadIdx.x;
  if (idx < 32768){ int n = idx >> 7, k = idx & 127; Wt1l[idx] = f2bf(Wl1[k*C1_ + n]); }
  else if (idx < 65536){ int j = idx - 32768; int n = j >> 7, k = j & 127; Wt1r[j] = f2bf(Wr1[k*C1_ + n]); }
  else if (idx < 77824){ int j = idx - 65536; int n = j >> 8, k = j & 255; Wt2l[j] = f2bf(Wl2[k*OUT_ + n]); }
  else if (idx < 90112){ int j = idx - 77824; int n = j >> 8, k = j & 255; Wt2r[j] = f2bf(Wr2[k*OUT_ + n]); }
}

// ------- fused GEMM1 v5: operand-swapped MFMA -> C^T lane layout -> direct stores -------
// JOURNAL:
//  R0 (107.5us): Cs-bounce epilogue. 64 scalar LDS writes + 2 barriers/pass; 1.6M LDS
//     bank conflicts; MfmaUtil 9.4 / VALU 14 / HBM 33% — latency-bound, 3 blocks/CU.
//  R1/R2 FAILED: reg-cap 4waves & pf[8] prefetch both spill (acc 64 + bfr 64 ~ 148 regs).
//  R3 FAILED: 8-wave split w/ per-ks B reloads: Occ 42% but ILP broken -> 148us.
//  v5: mfma(bfr, af, acc) computes C^T: lane l15 = output ROW m, (q*4+rg) = output COL n
//     -> lane packs 4 consecutive cols as ushort4 (8B); lanes {l15,+16,+32,+48} form 32B
//     contiguous row segments; adjacent nt fills the line. Deletes Cs (LDS 51.2->17.4KB),
//     64 LDS writes, 8 LDS reads and 2 barriers per pass. Numerically identical.
__global__ __launch_bounds__(256, 3) void gemm1_fused(
    const float* __restrict__ X,
    const unsigned short* __restrict__ Wtl, const unsigned short* __restrict__ Wtr,
    const float* __restrict__ bl, const float* __restrict__ br,
    unsigned short* __restrict__ outl, unsigned short* __restrict__ outr)
{
  __shared__ unsigned short As[64][136];   // +8 pad: 2-way bank aliasing only (free)
  const int t = threadIdx.x;
  const int lane = t & 63, wave = t >> 6;
  const int row0 = blockIdx.x << 6;
  const int l15 = lane & 15, q = lane >> 4;
  const int wcol = wave << 6;
  const int c4 = t & 31;

  #pragma unroll
  for (int i = 0; i < 8; ++i){
    int r = (i<<3) + (t>>5);
    float4 xv = *(const float4*)(X + ((size_t)(row0 + r) << 7) + (c4<<2));
    ushort4 s; s.x=f2bf(xv.x); s.y=f2bf(xv.y); s.z=f2bf(xv.z); s.w=f2bf(xv.w);
    *(ushort4*)(&As[r][c4<<2]) = s;
  }
  __syncthreads();   // only barrier in the block: As read-only afterwards

  const int npass = (row0 < N1_) ? 2 : 1;
  for (int pass = 0; pass < npass; ++pass){
    const unsigned short* Wt = pass ? Wtr : Wtl;
    const float* bias = pass ? br : bl;
    unsigned short* out = pass ? outr : outl;

    bfrag8 bfr[4][4];
    #pragma unroll
    for (int nt = 0; nt < 4; ++nt)
      #pragma unroll
      for (int ks = 0; ks < 4; ++ks)
        bfr[nt][ks] = *(const bfrag8*)(Wt + (size_t)(wcol + (nt<<4) + l15)*128 + (ks<<5) + (q<<3));

    ffrag4 z = {0.f, 0.f, 0.f, 0.f};
    ffrag4 acc[4][4];
    #pragma unroll
    for (int mt = 0; mt < 4; ++mt)
      #pragma unroll
      for (int nt = 0; nt < 4; ++nt) acc[mt][nt] = z;

    // swapped operands: D'[n][m] = sum_k Wt[n][k]*As[m][k] = C[m][n]
    // lane layout of acc[mt][nt]: row m = mt*16 + l15, cols n = wcol + nt*16 + q*4 + rg
    #pragma unroll
    for (int mt = 0; mt < 4; ++mt){
      #pragma unroll
      for (int ks = 0; ks < 4; ++ks){
        bfrag8 af = *(const bfrag8*)(&As[(mt<<4) + l15][(ks<<5) + (q<<3)]);
        #pragma unroll
        for (int nt = 0; nt < 4; ++nt)
          acc[mt][nt] = __builtin_amdgcn_mfma_f32_16x16x32_bf16(bfr[nt][ks], af, acc[mt][nt], 0, 0, 0);
      }
    }

    float4 bb[4];
    #pragma unroll
    for (int nt = 0; nt < 4; ++nt)
      bb[nt] = *(const float4*)(bias + wcol + (nt<<4) + (q<<2));

    #pragma unroll
    for (int mt = 0; mt < 4; ++mt){
      const size_t rbase = ((size_t)(row0 + (mt<<4) + l15) << 8);
      #pragma unroll
      for (int nt = 0; nt < 4; ++nt){
        ushort4 s;
        s.x = f2bf(acc[mt][nt][0] + bb[nt].x);
        s.y = f2bf(acc[mt][nt][1] + bb[nt].y);
        s.z = f2bf(acc[mt][nt][2] + bb[nt].z);
        s.w = f2bf(acc[mt][nt][3] + bb[nt].w);
        *(ushort4*)(out + rbase + wcol + (nt<<4) + (q<<2)) = s;
      }
    }
  }
}

// ------- fused GEMM2: [M,256] bf16 @ Wt2[48][256] + b -> f32 [M][64] zero-padded -------
__global__ __launch_bounds__(256) void gemm2_fused(
    const unsigned short* __restrict__ Hin,
    const unsigned short* __restrict__ Wtl, const unsigned short* __restrict__ Wtr,
    const float* __restrict__ bl, const float* __restrict__ br,
    float* __restrict__ outl, float* __restrict__ outr)
{
  __shared__ unsigned short As2[64][264];
  __shared__ unsigned short Bs2[48][264];
  const int t = threadIdx.x;
  const int lane = t & 63, wave = t >> 6;
  const int row0 = blockIdx.x << 6;
  const int l15 = lane & 15, q = lane >> 4;
  const int c32 = t & 31;

  #pragma unroll
  for (int i = 0; i < 8; ++i){
    int r = (i<<3) + (t>>5);
    *(bfrag8*)(&As2[r][c32<<3]) = *(const bfrag8*)(Hin + ((size_t)(row0 + r) << 8) + (c32<<3));
  }

  const int npass = (row0 < N2_) ? 2 : 1;
  for (int pass = 0; pass < npass; ++pass){
    const unsigned short* Wt = pass ? Wtr : Wtl;
    const float* bias = pass ? br : bl;
    float* out = pass ? outr : outl;

    if (pass) __syncthreads();          // prior mfma done before Bs2 overwrite
    #pragma unroll
    for (int i = 0; i < 6; ++i){
      int idx = i*256 + t;
      int r = idx >> 5, c = (idx & 31) << 3;
      *(bfrag8*)(&Bs2[r][c]) = *(const bfrag8*)(Wt + (size_t)r*256 + c);
    }
    __syncthreads();                    // also covers As2 staging on pass 0

    ffrag4 z = {0.f, 0.f, 0.f, 0.f};
    ffrag4 acc[3] = {z, z, z};
    #pragma unroll
    for (int ks = 0; ks < 8; ++ks){
      bfrag8 af = *(const bfrag8*)(&As2[(wave<<4) + l15][(ks<<5) + (q<<3)]);
      #pragma unroll
      for (int nt = 0; nt < 3; ++nt){
        bfrag8 bf = *(const bfrag8*)(&Bs2[(nt<<4) + l15][(ks<<5) + (q<<3)]);
        acc[nt] = __builtin_amdgcn_mfma_f32_16x16x32_bf16(af, bf, acc[nt], 0, 0, 0);
      }
    }
    #pragma unroll
    for (int nt = 0; nt < 3; ++nt){
      int col = (nt<<4) + l15;
      float bb = bias[col];
      #pragma unroll
      for (int rg = 0; rg < 4; ++rg){
        int row = row0 + (wave<<4) + (q<<2) + rg;
        out[(size_t)row*OUTP_ + col] = acc[nt][rg] + bb;
      }
    }
    #pragma unroll
    for (int rg = 0; rg < 4; ++rg){     // zero pad cols 48..63
      int row = row0 + (wave<<4) + (q<<2) + rg;
      out[(size_t)row*OUTP_ + 48 + l15] = 0.f;
    }
  }
}

// ---------------- CSR build: 3 kernels ----------------
__global__ void hist_both(const int* __restrict__ dst1, const int* __restrict__ dst2,
                          int* __restrict__ cnt1, int* __restrict__ cnt2, int E1, int E2){
  int i = blockIdx.x*256 + threadIdx.x;
  if (i < E1) atomicAdd(&cnt1[dst1[i]], 1);
  else if (i < E1 + E2) atomicAdd(&cnt2[dst2[i - E1]], 1);
}

__global__ __launch_bounds__(256) void scan_atomic_both(
    const int* __restrict__ cnt1, const int* __restrict__ cnt2,
    int* __restrict__ off1, int* __restrict__ off2,
    int* __restrict__ cur1, int* __restrict__ cur2,
    int* __restrict__ gpair, int n1, int n2, int nb1){
  __shared__ int s[256];
  __shared__ int base_s;
  const int* in; int* off; int* cur; int* g; int n; int b;
  if ((int)blockIdx.x < nb1){ in = cnt1; off = off1; cur = cur1; g = gpair;     n = n1; b = blockIdx.x; }
  else                      { in = cnt2; off = off2; cur = cur2; g = gpair + 1; n = n2; b = blockIdx.x - nb1; }
  int t = threadIdx.x, i = b*256 + t;
  int v = (i < n) ? in[i] : 0;
  s[t] = v; __syncthreads();
  #pragma unroll
  for (int d = 1; d < 256; d <<= 1){
    int u = (t >= d) ? s[t-d] : 0;
    __syncthreads();
    s[t] += u; __syncthreads();
  }
  if (t == 255) base_s = atomicAdd(g, s[255]);   // claim this block's range
  __syncthreads();
  if (i < n){
    int o = s[t] - v + base_s;
    off[i] = o; cur[i] = o;
  }
}

__global__ void scatter_both(const int* __restrict__ src1, const int* __restrict__ dst1,
                             const int* __restrict__ src2, const int* __restrict__ dst2,
                             int* __restrict__ cur1, int* __restrict__ cur2,
                             int* __restrict__ perm1, int* __restrict__ perm2, int E1, int E2){
  int i = blockIdx.x*256 + threadIdx.x;
  if (i < E1){
    int pos = atomicAdd(&cur1[dst1[i]], 1);
    perm1[pos] = src1[i];
  } else if (i < E1 + E2){
    int j = i - E1;
    int pos = atomicAdd(&cur2[dst2[j]], 1);
    perm2[pos] = src2[j];
  }
}

// ---------- fused layer-1 aggregation: wave/node, 2 edges/iter, 1-ahead gather prefetch ----------
__global__ __launch_bounds__(256) void gat_aggregate1(
    const unsigned short* __restrict__ xl, const unsigned short* __restrict__ xr,
    const int* __restrict__ offsets, const int* __restrict__ counts,
    const int* __restrict__ perm, const float* __restrict__ att,
    const float* __restrict__ bias, unsigned short* __restrict__ hout, int n)
{
  int node = (blockIdx.x << 2) + (threadIdx.x >> 6);
  if (node >= n) return;
  const int lane = threadIdx.x & 63;
  const int slot = lane >> 5;          // edge parity
  const int sub  = lane & 31;
  const int elem = sub << 3;           // 8 channels per lane (head = sub>>3)
  const unsigned int ebyte = (unsigned)elem << 1;
  const char* xlb = (const char*)xl;

  const int st = offsets[node], cnt = counts[node];
  uint4 ru = *(const uint4*)(xr + ((size_t)node << 8) + elem);
  float r[8];
  unpack2(ru.x, r[0], r[1]); unpack2(ru.y, r[2], r[3]);
  unpack2(ru.z, r[4], r[5]); unpack2(ru.w, r[6], r[7]);
  float4 al = *(const float4*)(att + elem);
  float4 ah = *(const float4*)(att + elem + 4);
  float a[8] = {al.x, al.y, al.z, al.w, ah.x, ah.y, ah.z, ah.w};

  float acc[8] = {0,0,0,0,0,0,0,0};
  float den = 0.f;

  for (int jb = 0; jb < cnt; jb += 64){
    int m = cnt - jb; if (m > 64) m = 64;
    int pv = (lane < m) ? perm[st + jb + lane] : 0;
    int s_cur = __shfl(pv, slot);
    uint4 xc = *(const uint4*)(xlb + (((unsigned)s_cur << 9) + ebyte));
    for (int j = 0; j < m; j += 2){
      int s_next = __shfl(pv, (j + 2 + slot) & 63);     // out-of-range -> pv=0 lanes (safe)
      uint4 xn = *(const uint4*)(xlb + (((unsigned)s_next << 9) + ebyte));  // prefetch j+2
      float x[8];
      unpack2(xc.x, x[0], x[1]); unpack2(xc.y, x[2], x[3]);
      unpack2(xc.z, x[4], x[5]); unpack2(xc.w, x[6], x[7]);
      float p = 0.f;
      #pragma unroll
      for (int i = 0; i < 8; ++i){
        float v = x[i] + r[i];
        float e = fmaf(NEG_, fminf(v, 0.f), fmaxf(v, 0.f));
        p = fmaf(e, a[i], p);
      }
      p += __shfl_xor(p, 1);
      p += __shfl_xor(p, 2);
      p += __shfl_xor(p, 4);         // full 64-ch head dot on all 8 lanes
      float ex = __expf(p);          // |alpha| bounded -> native exp safe
      ex = (j + slot < m) ? ex : 0.f;
      den += ex;
      #pragma unroll
      for (int i = 0; i < 8; ++i) acc[i] = fmaf(ex, x[i], acc[i]);
      xc = xn;
    }
  }
  den += __shfl_xor(den, 32);
  #pragma unroll
  for (int i = 0; i < 8; ++i) acc[i] += __shfl_xor(acc[i], 32);

  if (slot == 0){
    float w = 1.f / (den + 1e-16f);
    float4 bl = *(const float4*)(bias + elem);
    float4 bh = *(const float4*)(bias + elem + 4);
    float b[8] = {bl.x, bl.y, bl.z, bl.w, bh.x, bh.y, bh.z, bh.w};
    unsigned int o[4];
    #pragma unroll
    for (int i = 0; i < 4; ++i){
      unsigned short lo = f2bf(fmaxf(fmaf(acc[2*i],   w, b[2*i]),   0.f));
      unsigned short hi = f2bf(fmaxf(fmaf(acc[2*i+1], w, b[2*i+1]), 0.f));
      o[i] = (unsigned)lo | ((unsigned)hi << 16);
    }
    *(uint4*)(hout + ((size_t)node << 8) + elem) = make_uint4(o[0], o[1], o[2], o[3]);
  }
}

// ---------- fused layer-2 aggregation + log_softmax: wave/node, 4 edges/iter, prefetch ----------
__global__ __launch_bounds__(256) void gat_aggregate2(
    const float* __restrict__ xl, const float* __restrict__ xr,   // padded [.,64]
    const int* __restrict__ offsets, const int* __restrict__ counts,
    const int* __restrict__ perm, const float* __restrict__ att,
    const float* __restrict__ bias, float* __restrict__ out, int n)
{
  int node = (blockIdx.x << 2) + (threadIdx.x >> 6);
  if (node >= n) return;
  const int lane = threadIdx.x & 63;
  const int slot = lane >> 4;          // 0..3
  const int sub  = lane & 15;          // 4 channels (pad beyond 48)
  const bool realc = sub < 12;

  const int st = offsets[node], cnt = counts[node];
  float4 r = *(const float4*)(xr + (size_t)node*OUTP_ + (sub<<2));   // pads are 0
  float4 a = realc ? *(const float4*)(att + (sub<<2)) : make_float4(0,0,0,0);
  float4 acc = make_float4(0,0,0,0);
  float den = 0.f;

  for (int jb = 0; jb < cnt; jb += 64){
    int m = cnt - jb; if (m > 64) m = 64;
    int pv = (lane < m) ? perm[st + jb + lane] : 0;
    int s_cur = __shfl(pv, slot);
    float4 xc = *(const float4*)(xl + (size_t)((unsigned)s_cur*OUTP_ + (sub<<2)));
    for (int j = 0; j < m; j += 4){
      int s_next = __shfl(pv, (j + 4 + slot) & 63);
      float4 xn = *(const float4*)(xl + (size_t)((unsigned)s_next*OUTP_ + (sub<<2)));
      float v0 = xc.x + r.x, v1 = xc.y + r.y, v2 = xc.z + r.z, v3 = xc.w + r.w;
      float p;
      p = fmaf(a.x, fmaf(NEG_, fminf(v0,0.f), fmaxf(v0,0.f)), 0.f);
      p = fmaf(a.y, fmaf(NEG_, fminf(v1,0.f), fmaxf(v1,0.f)), p);
      p = fmaf(a.z, fmaf(NEG_, fminf(v2,0.f), fmaxf(v2,0.f)), p);
      p = fmaf(a.w, fmaf(NEG_, fminf(v3,0.f), fmaxf(v3,0.f)), p);
      p += __shfl_xor(p, 1);
      p += __shfl_xor(p, 2);
      p += __shfl_xor(p, 4);
      p += __shfl_xor(p, 8);
      float ex = __expf(p);
      ex = (j + slot < m) ? ex : 0.f;
      den += ex;
      acc.x = fmaf(ex, xc.x, acc.x); acc.y = fmaf(ex, xc.y, acc.y);
      acc.z = fmaf(ex, xc.z, acc.z); acc.w = fmaf(ex, xc.w, acc.w);
      xc = xn;
    }
  }
  den += __shfl_xor(den, 16); den += __shfl_xor(den, 32);
  acc.x += __shfl_xor(acc.x, 16); acc.x += __shfl_xor(acc.x, 32);
  acc.y += __shfl_xor(acc.y, 16); acc.y += __shfl_xor(acc.y, 32);
  acc.z += __shfl_xor(acc.z, 16); acc.z += __shfl_xor(acc.z, 32);
  acc.w += __shfl_xor(acc.w, 16); acc.w += __shfl_xor(acc.w, 32);

  float w = 1.f / (den + 1e-16f);
  float4 b = realc ? *(const float4*)(bias + (sub<<2)) : make_float4(0,0,0,0);
  float v0 = fmaf(acc.x, w, b.x), v1 = fmaf(acc.y, w, b.y);
  float v2 = fmaf(acc.z, w, b.z), v3 = fmaf(acc.w, w, b.w);

  float mx = realc ? fmaxf(fmaxf(v0, v1), fmaxf(v2, v3)) : -3.0e38f;
  mx = fmaxf(mx, __shfl_xor(mx, 1)); mx = fmaxf(mx, __shfl_xor(mx, 2));
  mx = fmaxf(mx, __shfl_xor(mx, 4)); mx = fmaxf(mx, __shfl_xor(mx, 8));
  float es = realc ? (__expf(v0-mx) + __expf(v1-mx) + __expf(v2-mx) + __expf(v3-mx)) : 0.f;
  es += __shfl_xor(es, 1); es += __shfl_xor(es, 2);
  es += __shfl_xor(es, 4); es += __shfl_xor(es, 8);
  float ls = __logf(es);
  if (slot == 0 && realc){
    float4 o = make_float4(v0-mx-ls, v1-mx-ls, v2-mx-ls, v3-mx-ls);
    *(float4*)(out + (size_t)node*OUT_ + (sub<<2)) = o;
  }
}

extern "C" void kernel_launch(void* const* d_in, const int* in_sizes, int n_in,
                              void* d_out, int out_size, void* d_ws, size_t ws_size,
                              hipStream_t stream)
{
  const float* x    = (const float*)d_in[0];
  const float* Wl1  = (const float*)d_in[1];
  const float* bl1  = (const float*)d_in[2];
  const float* Wr1  = (const float*)d_in[3];
  const float* br1  = (const float*)d_in[4];
  const float* att1 = (const float*)d_in[5];
  const float* bias1= (const float*)d_in[6];
  const float* Wl2  = (const float*)d_in[7];
  const float* bl2  = (const float*)d_in[8];
  const float* Wr2  = (const float*)d_in[9];
  const float* br2  = (const float*)d_in[10];
  const float* att2 = (const float*)d_in[11];
  const float* bias2= (const float*)d_in[12];
  const int* src1 = (const int*)d_in[13];
  const int* dst1 = (const int*)d_in[14];
  const int* src2 = (const int*)d_in[15];
  const int* dst2 = (const int*)d_in[16];
  const int E1 = in_sizes[13];
  const int E2 = in_sizes[15];
  (void)n_in; (void)out_size; (void)ws_size;

  // ---- workspace layout (bytes), total ~275.5 MB ----
  char* ws = (char*)d_ws;
  unsigned short* xl1  = (unsigned short*)(ws + 0LL);          // bf16 [320000][256]
  unsigned short* xr1  = (unsigned short*)(ws + 163840000LL);  // bf16 [ 80000][256]
  unsigned short* hbuf = (unsigned short*)(ws + 204800000LL);  // bf16 [ 80000][256]
  float* xl2p   = (float*)(ws + 245760000LL);                  // f32  [ 80000][64] padded
  float* xr2p   = (float*)(ws + 266240000LL);                  // f32  [ 16000][64] padded
  int*   perm1  = (int*)  (ws + 270336000LL);                  // int  [800000]
  int*   perm2  = (int*)  (ws + 273536000LL);                  // int  [160000]
  int*   cnt1   = (int*)  (ws + 274176000LL);                  // int  [ 80000] (zeroed)
  int*   cnt2   = (int*)  (ws + 274496000LL);                  // int  [ 16000] (zeroed)
  int*   off1   = (int*)  (ws + 274560000LL);                  // int  [ 80000]
  int*   cur1   = (int*)  (ws + 274880000LL);                  // int  [ 80000]
  int*   off2   = (int*)  (ws + 275200000LL);                  // int  [ 16000]
  int*   cur2   = (int*)  (ws + 275264000LL);                  // int  [ 16000]
  int*   gpair  = (int*)  (ws + 275328000LL);                  // int  [     2] (zeroed)
  unsigned short* Wt1l = (unsigned short*)(ws + 275332096LL);  // bf16 [256][128]
  unsigned short* Wt1r = (unsigned short*)(ws + 275397632LL);  // bf16 [256][128]
  unsigned short* Wt2l = (unsigned short*)(ws + 275463168LL);  // bf16 [ 48][256]
  unsigned short* Wt2r = (unsigned short*)(ws + 275487744LL);  // bf16 [ 48][256]

  hipMemsetAsync(ws + 274176000LL, 0, 384000LL, stream);       // cnt1 + cnt2
  hipMemsetAsync(ws + 275328000LL, 0, 8LL, stream);            // gpair

  const int nb1 = (N1_ + 255) / 256;   // 313
  const int nb2 = (N2_ + 255) / 256;   // 63

  transpose_all<<<352, 256, 0, stream>>>(Wl1, Wr1, Wl2, Wr2, Wt1l, Wt1r, Wt2l, Wt2r);

  // CSR build for both edge sets
  hist_both       <<<(E1+E2+255)/256, 256, 0, stream>>>(dst1, dst2, cnt1, cnt2, E1, E2);
  scan_atomic_both<<<nb1+nb2, 256, 0, stream>>>(cnt1, cnt2, off1, off2, cur1, cur2,
                                                gpair, N1_, N2_, nb1);
  scatter_both    <<<(E1+E2+255)/256, 256, 0, stream>>>(src1, dst1, src2, dst2,
                                                        cur1, cur2, perm1, perm2, E1, E2);

  gemm1_fused<<<N0_/64, 256, 0, stream>>>(x, Wt1l, Wt1r, bl1, br1, xl1, xr1);

  gat_aggregate1<<<(N1_+3)/4, 256, 0, stream>>>(xl1, xr1, off1, cnt1, perm1,
                                                att1, bias1, hbuf, N1_);

  gemm2_fused<<<N1_/64, 256, 0, stream>>>(hbuf, Wt2l, Wt2r, bl2, br2, xl2p, xr2p);

  gat_aggregate2<<<(N2_+3)/4, 256, 0, stream>>>(xl2p, xr2p, off2, cnt2, perm2,
                                                att2, bias2, (float*)d_out, N2_);
}

// Round 6
// 573.491 us; speedup vs baseline: 1.0231x; 1.0231x over previous
//
#include <hip/hip_runtime.h>
#include <hip/hip_bf16.h>

#define N0_  320000
#define N1_  80000
#define N2_  16000
#define INC_ 128
#define HID_ 64
#define H1_  4
#define C1_  256   // H1*HID
#define OUT_ 48
#define OUTP_ 64   // padded layer-2 feature stride
#define NEG_ 0.2f

typedef __attribute__((ext_vector_type(8))) short bfrag8;   // 8 bf16 (4 VGPRs)
typedef __attribute__((ext_vector_type(4))) float ffrag4;   // 4 fp32 acc

__device__ __forceinline__ float bf2f(unsigned short u){
  unsigned int v = ((unsigned int)u) << 16;
  return __uint_as_float(v);
}
__device__ __forceinline__ unsigned short f2bf(float f){
  unsigned int u = __float_as_uint(f);
  u += 0x7FFFu + ((u >> 16) & 1u);   // round-to-nearest-even
  return (unsigned short)(u >> 16);
}
__device__ __forceinline__ void unpack2(unsigned int u, float& lo, float& hi){
  lo = __uint_as_float(u << 16);
  hi = __uint_as_float(u & 0xffff0000u);
}

// ---- all 4 weight transposes in one kernel (f32 [K][N] -> bf16 [N][K]) ----
__global__ void transpose_all(const float* __restrict__ Wl1, const float* __restrict__ Wr1,
                              const float* __restrict__ Wl2, const float* __restrict__ Wr2,
                              unsigned short* __restrict__ Wt1l, unsigned short* __restrict__ Wt1r,
                              unsigned short* __restrict__ Wt2l, unsigned short* __restrict__ Wt2r){
  int idx = blockIdx.x*256 + threadIdx.x;
  if (idx < 32768){ int n = idx >> 7, k = idx & 127; Wt1l[idx] = f2bf(Wl1[k*C1_ + n]); }
  else if (idx < 65536){ int j = idx - 32768; int n = j >> 7, k = j & 127; Wt1r[j] = f2bf(Wr1[k*C1_ + n]); }
  else if (idx < 77824){ int j = idx - 65536; int n = j >> 8, k = j & 255; Wt2l[j] = f2bf(Wl2[k*OUT_ + n]); }
  else if (idx < 90112){ int j = idx - 77824; int n = j >> 8, k = j & 255; Wt2r[j] = f2bf(Wr2[k*OUT_ + n]); }
}

// ------- fused GEMM1 (R0/R4-exact, 107.5us measured): stage A once; 2 passes -------
// JOURNAL — this kernel is PINNED after 4 failed restructures; do not touch without
// new counter evidence:
//  R1: launch_bounds(256,4) reg cap 128 < acc(64)+bfr(64)+addr -> spills, +50MB, 133us.
//  R2: +pf[8] f32 next-tile prefetch at (256,3) -> spills, +30MB, 124.6us.
//  R3: 512thr/8wave acc[2][4] + per-ks B reloads: no spills, Occ 42%, but ILP broken
//      (serial L2-load->MFMA chain) -> 148us. Occupancy is not the constraint; ILP is.
//  R5: operand-swapped C^T direct stores (no Cs): 32B scattered row segments ->
//      partial-sector WRITE-ALLOCATE RMW: FETCH +58MB, WRITE +115MB, 173us.
//      The Cs bounce's full 512B/wave row stores are LOAD-BEARING.
__global__ __launch_bounds__(256, 3) void gemm1_fused(
    const float* __restrict__ X,
    const unsigned short* __restrict__ Wtl, const unsigned short* __restrict__ Wtr,
    const float* __restrict__ bl, const float* __restrict__ br,
    unsigned short* __restrict__ outl, unsigned short* __restrict__ outr)
{
  __shared__ unsigned short As[64][136];   // +8 pad: 2-way bank aliasing only (free)
  __shared__ unsigned short Cs[64][264];   // epilogue bounce for coalesced stores
  const int t = threadIdx.x;
  const int lane = t & 63, wave = t >> 6;
  const int row0 = blockIdx.x << 6;
  const int l15 = lane & 15, q = lane >> 4;
  const int wcol = wave << 6;
  const int c4 = t & 31;

  #pragma unroll
  for (int i = 0; i < 8; ++i){
    int r = (i<<3) + (t>>5);
    float4 xv = *(const float4*)(X + ((size_t)(row0 + r) << 7) + (c4<<2));
    ushort4 s; s.x=f2bf(xv.x); s.y=f2bf(xv.y); s.z=f2bf(xv.z); s.w=f2bf(xv.w);
    *(ushort4*)(&As[r][c4<<2]) = s;
  }
  __syncthreads();

  const int npass = (row0 < N1_) ? 2 : 1;
  for (int pass = 0; pass < npass; ++pass){
    const unsigned short* Wt = pass ? Wtr : Wtl;
    const float* bias = pass ? br : bl;
    unsigned short* out = pass ? outr : outl;

    bfrag8 bfr[4][4];
    #pragma unroll
    for (int nt = 0; nt < 4; ++nt)
      #pragma unroll
      for (int ks = 0; ks < 4; ++ks)
        bfr[nt][ks] = *(const bfrag8*)(Wt + (size_t)(wcol + (nt<<4) + l15)*128 + (ks<<5) + (q<<3));

    ffrag4 z = {0.f, 0.f, 0.f, 0.f};
    ffrag4 acc[4][4];
    #pragma unroll
    for (int mt = 0; mt < 4; ++mt)
      #pragma unroll
      for (int nt = 0; nt < 4; ++nt) acc[mt][nt] = z;

    #pragma unroll
    for (int mt = 0; mt < 4; ++mt){
      #pragma unroll
      for (int ks = 0; ks < 4; ++ks){
        bfrag8 af = *(const bfrag8*)(&As[(mt<<4) + l15][(ks<<5) + (q<<3)]);
        #pragma unroll
        for (int nt = 0; nt < 4; ++nt)
          acc[mt][nt] = __builtin_amdgcn_mfma_f32_16x16x32_bf16(af, bfr[nt][ks], acc[mt][nt], 0, 0, 0);
      }
    }

    float bb[4];
    #pragma unroll
    for (int nt = 0; nt < 4; ++nt) bb[nt] = bias[wcol + (nt<<4) + l15];
    #pragma unroll
    for (int mt = 0; mt < 4; ++mt)
      #pragma unroll
      for (int nt = 0; nt < 4; ++nt)
        #pragma unroll
        for (int rg = 0; rg < 4; ++rg)
          Cs[(mt<<4) + (q<<2) + rg][wcol + (nt<<4) + l15] = f2bf(acc[mt][nt][rg] + bb[nt]);
    __syncthreads();
    #pragma unroll
    for (int i = 0; i < 8; ++i){
      int r = (i<<3) + (t>>5);
      *(bfrag8*)(out + ((size_t)(row0 + r) << 8) + (c4<<3)) = *(const bfrag8*)(&Cs[r][c4<<3]);
    }
    if (pass + 1 < npass) __syncthreads();   // protect Cs reuse
  }
}

// ------- fused GEMM2: [M,256] bf16 @ Wt2[48][256] + b -> f32 [M][64] zero-padded -------
__global__ __launch_bounds__(256) void gemm2_fused(
    const unsigned short* __restrict__ Hin,
    const unsigned short* __restrict__ Wtl, const unsigned short* __restrict__ Wtr,
    const float* __restrict__ bl, const float* __restrict__ br,
    float* __restrict__ outl, float* __restrict__ outr)
{
  __shared__ unsigned short As2[64][264];
  __shared__ unsigned short Bs2[48][264];
  const int t = threadIdx.x;
  const int lane = t & 63, wave = t >> 6;
  const int row0 = blockIdx.x << 6;
  const int l15 = lane & 15, q = lane >> 4;
  const int c32 = t & 31;

  #pragma unroll
  for (int i = 0; i < 8; ++i){
    int r = (i<<3) + (t>>5);
    *(bfrag8*)(&As2[r][c32<<3]) = *(const bfrag8*)(Hin + ((size_t)(row0 + r) << 8) + (c32<<3));
  }

  const int npass = (row0 < N2_) ? 2 : 1;
  for (int pass = 0; pass < npass; ++pass){
    const unsigned short* Wt = pass ? Wtr : Wtl;
    const float* bias = pass ? br : bl;
    float* out = pass ? outr : outl;

    if (pass) __syncthreads();          // prior mfma done before Bs2 overwrite
    #pragma unroll
    for (int i = 0; i < 6; ++i){
      int idx = i*256 + t;
      int r = idx >> 5, c = (idx & 31) << 3;
      *(bfrag8*)(&Bs2[r][c]) = *(const bfrag8*)(Wt + (size_t)r*256 + c);
    }
    __syncthreads();                    // also covers As2 staging on pass 0

    ffrag4 z = {0.f, 0.f, 0.f, 0.f};
    ffrag4 acc[3] = {z, z, z};
    #pragma unroll
    for (int ks = 0; ks < 8; ++ks){
      bfrag8 af = *(const bfrag8*)(&As2[(wave<<4) + l15][(ks<<5) + (q<<3)]);
      #pragma unroll
      for (int nt = 0; nt < 3; ++nt){
        bfrag8 bf = *(const bfrag8*)(&Bs2[(nt<<4) + l15][(ks<<5) + (q<<3)]);
        acc[nt] = __builtin_amdgcn_mfma_f32_16x16x32_bf16(af, bf, acc[nt], 0, 0, 0);
      }
    }
    #pragma unroll
    for (int nt = 0; nt < 3; ++nt){
      int col = (nt<<4) + l15;
      float bb = bias[col];
      #pragma unroll
      for (int rg = 0; rg < 4; ++rg){
        int row = row0 + (wave<<4) + (q<<2) + rg;
        out[(size_t)row*OUTP_ + col] = acc[nt][rg] + bb;
      }
    }
    #pragma unroll
    for (int rg = 0; rg < 4; ++rg){     // zero pad cols 48..63
      int row = row0 + (wave<<4) + (q<<2) + rg;
      out[(size_t)row*OUTP_ + 48 + l15] = 0.f;
    }
  }
}

// ---------------- CSR build: 3 kernels ----------------
__global__ void hist_both(const int* __restrict__ dst1, const int* __restrict__ dst2,
                          int* __restrict__ cnt1, int* __restrict__ cnt2, int E1, int E2){
  int i = blockIdx.x*256 + threadIdx.x;
  if (i < E1) atomicAdd(&cnt1[dst1[i]], 1);
  else if (i < E1 + E2) atomicAdd(&cnt2[dst2[i - E1]], 1);
}

__global__ __launch_bounds__(256) void scan_atomic_both(
    const int* __restrict__ cnt1, const int* __restrict__ cnt2,
    int* __restrict__ off1, int* __restrict__ off2,
    int* __restrict__ cur1, int* __restrict__ cur2,
    int* __restrict__ gpair, int n1, int n2, int nb1){
  __shared__ int s[256];
  __shared__ int base_s;
  const int* in; int* off; int* cur; int* g; int n; int b;
  if ((int)blockIdx.x < nb1){ in = cnt1; off = off1; cur = cur1; g = gpair;     n = n1; b = blockIdx.x; }
  else                      { in = cnt2; off = off2; cur = cur2; g = gpair + 1; n = n2; b = blockIdx.x - nb1; }
  int t = threadIdx.x, i = b*256 + t;
  int v = (i < n) ? in[i] : 0;
  s[t] = v; __syncthreads();
  #pragma unroll
  for (int d = 1; d < 256; d <<= 1){
    int u = (t >= d) ? s[t-d] : 0;
    __syncthreads();
    s[t] += u; __syncthreads();
  }
  if (t == 255) base_s = atomicAdd(g, s[255]);   // claim this block's range
  __syncthreads();
  if (i < n){
    int o = s[t] - v + base_s;
    off[i] = o; cur[i] = o;
  }
}

__global__ void scatter_both(const int* __restrict__ src1, const int* __restrict__ dst1,
                             const int* __restrict__ src2, const int* __restrict__ dst2,
                             int* __restrict__ cur1, int* __restrict__ cur2,
                             int* __restrict__ perm1, int* __restrict__ perm2, int E1, int E2){
  int i = blockIdx.x*256 + threadIdx.x;
  if (i < E1){
    int pos = atomicAdd(&cur1[dst1[i]], 1);
    perm1[pos] = src1[i];
  } else if (i < E1 + E2){
    int j = i - E1;
    int pos = atomicAdd(&cur2[dst2[j]], 1);
    perm2[pos] = src2[j];
  }
}

// ---------- fused layer-1 aggregation v2: wave/node, 4 edges/iter, 16 ch/lane ----------
// R6 JOURNAL: was 2 edges/iter, 8ch/lane (1 outstanding 512B gather per wave).
// Random-gather from 164MB L3-resident table ~500cy latency; with ~5 inner iters/node
// the exposed latency dominates. v2: slot=lane>>4 -> 4 edges in flight (8 uint4 loads),
// 2-hop shuffle reduce (was 3). Same per-edge VALU; reduction order change within tol.
__global__ __launch_bounds__(256) void gat_aggregate1(
    const unsigned short* __restrict__ xl, const unsigned short* __restrict__ xr,
    const int* __restrict__ offsets, const int* __restrict__ counts,
    const int* __restrict__ perm, const float* __restrict__ att,
    const float* __restrict__ bias, unsigned short* __restrict__ hout, int n)
{
  int node = (blockIdx.x << 2) + (threadIdx.x >> 6);
  if (node >= n) return;
  const int lane = threadIdx.x & 63;
  const int slot = lane >> 4;          // edge index within quad (0..3)
  const int sub  = lane & 15;
  const int elem = sub << 4;           // 16 channels per lane (head = sub>>2)
  const unsigned int ebyte = (unsigned)elem << 1;   // 32B per lane
  const char* xlb = (const char*)xl;

  const int st = offsets[node], cnt = counts[node];
  uint4 ru0 = *(const uint4*)(xr + ((size_t)node << 8) + elem);
  uint4 ru1 = *(const uint4*)(xr + ((size_t)node << 8) + elem + 8);
  float r[16];
  unpack2(ru0.x, r[0], r[1]);  unpack2(ru0.y, r[2], r[3]);
  unpack2(ru0.z, r[4], r[5]);  unpack2(ru0.w, r[6], r[7]);
  unpack2(ru1.x, r[8], r[9]);  unpack2(ru1.y, r[10], r[11]);
  unpack2(ru1.z, r[12], r[13]); unpack2(ru1.w, r[14], r[15]);
  float a[16];
  #pragma unroll
  for (int i = 0; i < 4; ++i){
    float4 av = *(const float4*)(att + elem + (i<<2));
    a[4*i] = av.x; a[4*i+1] = av.y; a[4*i+2] = av.z; a[4*i+3] = av.w;
  }

  float acc[16];
  #pragma unroll
  for (int i = 0; i < 16; ++i) acc[i] = 0.f;
  float den = 0.f;

  for (int jb = 0; jb < cnt; jb += 64){
    int m = cnt - jb; if (m > 64) m = 64;
    int pv = (lane < m) ? perm[st + jb + lane] : 0;
    int s_cur = __shfl(pv, slot);
    uint4 xc0 = *(const uint4*)(xlb + (((unsigned)s_cur << 9) + ebyte));
    uint4 xc1 = *(const uint4*)(xlb + (((unsigned)s_cur << 9) + ebyte + 16));
    for (int j = 0; j < m; j += 4){
      int s_next = __shfl(pv, (j + 4 + slot) & 63);   // out-of-range -> pv=0 lanes (safe)
      uint4 xn0 = *(const uint4*)(xlb + (((unsigned)s_next << 9) + ebyte));       // prefetch
      uint4 xn1 = *(const uint4*)(xlb + (((unsigned)s_next << 9) + ebyte + 16));
      float x[16];
      unpack2(xc0.x, x[0], x[1]);  unpack2(xc0.y, x[2], x[3]);
      unpack2(xc0.z, x[4], x[5]);  unpack2(xc0.w, x[6], x[7]);
      unpack2(xc1.x, x[8], x[9]);  unpack2(xc1.y, x[10], x[11]);
      unpack2(xc1.z, x[12], x[13]); unpack2(xc1.w, x[14], x[15]);
      float p = 0.f;
      #pragma unroll
      for (int i = 0; i < 16; ++i){
        float v = x[i] + r[i];
        float e = fmaf(NEG_, fminf(v, 0.f), fmaxf(v, 0.f));
        p = fmaf(e, a[i], p);
      }
      p += __shfl_xor(p, 1);
      p += __shfl_xor(p, 2);         // 4-lane group -> full 64-ch head dot
      float ex = __expf(p);          // |alpha| bounded -> native exp safe
      ex = (j + slot < m) ? ex : 0.f;
      den += ex;
      #pragma unroll
      for (int i = 0; i < 16; ++i) acc[i] = fmaf(ex, x[i], acc[i]);
      xc0 = xn0; xc1 = xn1;
    }
  }
  den += __shfl_xor(den, 16); den += __shfl_xor(den, 32);
  #pragma unroll
  for (int i = 0; i < 16; ++i){
    acc[i] += __shfl_xor(acc[i], 16);
    acc[i] += __shfl_xor(acc[i], 32);
  }

  if (slot == 0){
    float w = 1.f / (den + 1e-16f);
    float b[16];
    #pragma unroll
    for (int i = 0; i < 4; ++i){
      float4 bv = *(const float4*)(bias + elem + (i<<2));
      b[4*i] = bv.x; b[4*i+1] = bv.y; b[4*i+2] = bv.z; b[4*i+3] = bv.w;
    }
    unsigned int o[8];
    #pragma unroll
    for (int i = 0; i < 8; ++i){
      unsigned short lo = f2bf(fmaxf(fmaf(acc[2*i],   w, b[2*i]),   0.f));
      unsigned short hi = f2bf(fmaxf(fmaf(acc[2*i+1], w, b[2*i+1]), 0.f));
      o[i] = (unsigned)lo | ((unsigned)hi << 16);
    }
    *(uint4*)(hout + ((size_t)node << 8) + elem)     = make_uint4(o[0], o[1], o[2], o[3]);
    *(uint4*)(hout + ((size_t)node << 8) + elem + 8) = make_uint4(o[4], o[5], o[6], o[7]);
  }
}

// ---------- fused layer-2 aggregation + log_softmax: wave/node, 4 edges/iter, prefetch ----------
__global__ __launch_bounds__(256) void gat_aggregate2(
    const float* __restrict__ xl, const float* __restrict__ xr,   // padded [.,64]
    const int* __restrict__ offsets, const int* __restrict__ counts,
    const int* __restrict__ perm, const float* __restrict__ att,
    const float* __restrict__ bias, float* __restrict__ out, int n)
{
  int node = (blockIdx.x << 2) + (threadIdx.x >> 6);
  if (node >= n) return;
  const int lane = threadIdx.x & 63;
  const int slot = lane >> 4;          // 0..3
  const int sub  = lane & 15;          // 4 channels (pad beyond 48)
  const bool realc = sub < 12;

  const int st = offsets[node], cnt = counts[node];
  float4 r = *(const float4*)(xr + (size_t)node*OUTP_ + (sub<<2));   // pads are 0
  float4 a = realc ? *(const float4*)(att + (sub<<2)) : make_float4(0,0,0,0);
  float4 acc = make_float4(0,0,0,0);
  float den = 0.f;

  for (int jb = 0; jb < cnt; jb += 64){
    int m = cnt - jb; if (m > 64) m = 64;
    int pv = (lane < m) ? perm[st + jb + lane] : 0;
    int s_cur = __shfl(pv, slot);
    float4 xc = *(const float4*)(xl + (size_t)((unsigned)s_cur*OUTP_ + (sub<<2)));
    for (int j = 0; j < m; j += 4){
      int s_next = __shfl(pv, (j + 4 + slot) & 63);
      float4 xn = *(const float4*)(xl + (size_t)((unsigned)s_next*OUTP_ + (sub<<2)));
      float v0 = xc.x + r.x, v1 = xc.y + r.y, v2 = xc.z + r.z, v3 = xc.w + r.w;
      float p;
      p = fmaf(a.x, fmaf(NEG_, fminf(v0,0.f), fmaxf(v0,0.f)), 0.f);
      p = fmaf(a.y, fmaf(NEG_, fminf(v1,0.f), fmaxf(v1,0.f)), p);
      p = fmaf(a.z, fmaf(NEG_, fminf(v2,0.f), fmaxf(v2,0.f)), p);
      p = fmaf(a.w, fmaf(NEG_, fminf(v3,0.f), fmaxf(v3,0.f)), p);
      p += __shfl_xor(p, 1);
      p += __shfl_xor(p, 2);
      p += __shfl_xor(p, 4);
      p += __shfl_xor(p, 8);
      float ex = __expf(p);
      ex = (j + slot < m) ? ex : 0.f;
      den += ex;
      acc.x = fmaf(ex, xc.x, acc.x); acc.y = fmaf(ex, xc.y, acc.y);
      acc.z = fmaf(ex, xc.z, acc.z); acc.w = fmaf(ex, xc.w, acc.w);
      xc = xn;
    }
  }
  den += __shfl_xor(den, 16); den += __shfl_xor(den, 32);
  acc.x += __shfl_xor(acc.x, 16); acc.x += __shfl_xor(acc.x, 32);
  acc.y += __shfl_xor(acc.y, 16); acc.y += __shfl_xor(acc.y, 32);
  acc.z += __shfl_xor(acc.z, 16); acc.z += __shfl_xor(acc.z, 32);
  acc.w += __shfl_xor(acc.w, 16); acc.w += __shfl_xor(acc.w, 32);

  float w = 1.f / (den + 1e-16f);
  float4 b = realc ? *(const float4*)(bias + (sub<<2)) : make_float4(0,0,0,0);
  float v0 = fmaf(acc.x, w, b.x), v1 = fmaf(acc.y, w, b.y);
  float v2 = fmaf(acc.z, w, b.z), v3 = fmaf(acc.w, w, b.w);

  float mx = realc ? fmaxf(fmaxf(v0, v1), fmaxf(v2, v3)) : -3.0e38f;
  mx = fmaxf(mx, __shfl_xor(mx, 1)); mx = fmaxf(mx, __shfl_xor(mx, 2));
  mx = fmaxf(mx, __shfl_xor(mx, 4)); mx = fmaxf(mx, __shfl_xor(mx, 8));
  float es = realc ? (__expf(v0-mx) + __expf(v1-mx) + __expf(v2-mx) + __expf(v3-mx)) : 0.f;
  es += __shfl_xor(es, 1); es += __shfl_xor(es, 2);
  es += __shfl_xor(es, 4); es += __shfl_xor(es, 8);
  float ls = __logf(es);
  if (slot == 0 && realc){
    float4 o = make_float4(v0-mx-ls, v1-mx-ls, v2-mx-ls, v3-mx-ls);
    *(float4*)(out + (size_t)node*OUT_ + (sub<<2)) = o;
  }
}

extern "C" void kernel_launch(void* const* d_in, const int* in_sizes, int n_in,
                              void* d_out, int out_size, void* d_ws, size_t ws_size,
                              hipStream_t stream)
{
  const float* x    = (const float*)d_in[0];
  const float* Wl1  = (const float*)d_in[1];
  const float* bl1  = (const float*)d_in[2];
  const float* Wr1  = (const float*)d_in[3];
  const float* br1  = (const float*)d_in[4];
  const float* att1 = (const float*)d_in[5];
  const float* bias1= (const float*)d_in[6];
  const float* Wl2  = (const float*)d_in[7];
  const float* bl2  = (const float*)d_in[8];
  const float* Wr2  = (const float*)d_in[9];
  const float* br2  = (const float*)d_in[10];
  const float* att2 = (const float*)d_in[11];
  const float* bias2= (const float*)d_in[12];
  const int* src1 = (const int*)d_in[13];
  const int* dst1 = (const int*)d_in[14];
  const int* src2 = (const int*)d_in[15];
  const int* dst2 = (const int*)d_in[16];
  const int E1 = in_sizes[13];
  const int E2 = in_sizes[15];
  (void)n_in; (void)out_size; (void)ws_size;

  // ---- workspace layout (bytes), total ~275.5 MB ----
  char* ws = (char*)d_ws;
  unsigned short* xl1  = (unsigned short*)(ws + 0LL);          // bf16 [320000][256]
  unsigned short* xr1  = (unsigned short*)(ws + 163840000LL);  // bf16 [ 80000][256]
  unsigned short* hbuf = (unsigned short*)(ws + 204800000LL);  // bf16 [ 80000][256]
  float* xl2p   = (float*)(ws + 245760000LL);                  // f32  [ 80000][64] padded
  float* xr2p   = (float*)(ws + 266240000LL);                  // f32  [ 16000][64] padded
  int*   perm1  = (int*)  (ws + 270336000LL);                  // int  [800000]
  int*   perm2  = (int*)  (ws + 273536000LL);                  // int  [160000]
  int*   cnt1   = (int*)  (ws + 274176000LL);                  // int  [ 80000] (zeroed)
  int*   cnt2   = (int*)  (ws + 274496000LL);                  // int  [ 16000] (zeroed)
  int*   off1   = (int*)  (ws + 274560000LL);                  // int  [ 80000]
  int*   cur1   = (int*)  (ws + 274880000LL);                  // int  [ 80000]
  int*   off2   = (int*)  (ws + 275200000LL);                  // int  [ 16000]
  int*   cur2   = (int*)  (ws + 275264000LL);                  // int  [ 16000]
  int*   gpair  = (int*)  (ws + 275328000LL);                  // int  [     2] (zeroed)
  unsigned short* Wt1l = (unsigned short*)(ws + 275332096LL);  // bf16 [256][128]
  unsigned short* Wt1r = (unsigned short*)(ws + 275397632LL);  // bf16 [256][128]
  unsigned short* Wt2l = (unsigned short*)(ws + 275463168LL);  // bf16 [ 48][256]
  unsigned short* Wt2r = (unsigned short*)(ws + 275487744LL);  // bf16 [ 48][256]

  hipMemsetAsync(ws + 274176000LL, 0, 384000LL, stream);       // cnt1 + cnt2
  hipMemsetAsync(ws + 275328000LL, 0, 8LL, stream);            // gpair

  const int nb1 = (N1_ + 255) / 256;   // 313
  const int nb2 = (N2_ + 255) / 256;   // 63

  transpose_all<<<352, 256, 0, stream>>>(Wl1, Wr1, Wl2, Wr2, Wt1l, Wt1r, Wt2l, Wt2r);

  // CSR build for both edge sets
  hist_both       <<<(E1+E2+255)/256, 256, 0, stream>>>(dst1, dst2, cnt1, cnt2, E1, E2);
  scan_atomic_both<<<nb1+nb2, 256, 0, stream>>>(cnt1, cnt2, off1, off2, cur1, cur2,
                                                gpair, N1_, N2_, nb1);
  scatter_both    <<<(E1+E2+255)/256, 256, 0, stream>>>(src1, dst1, src2, dst2,
                                                        cur1, cur2, perm1, perm2, E1, E2);

  gemm1_fused<<<N0_/64, 256, 0, stream>>>(x, Wt1l, Wt1r, bl1, br1, xl1, xr1);

  gat_aggregate1<<<(N1_+3)/4, 256, 0, stream>>>(xl1, xr1, off1, cnt1, perm1,
                                                att1, bias1, hbuf, N1_);

  gemm2_fused<<<N1_/64, 256, 0, stream>>>(hbuf, Wt2l, Wt2r, bl2, br2, xl2p, xr2p);

  gat_aggregate2<<<(N2_+3)/4, 256, 0, stream>>>(xl2p, xr2p, off2, cnt2, perm2,
                                                att2, bias2, (float*)d_out, N2_);
}

// Round 7
// 572.717 us; speedup vs baseline: 1.0245x; 1.0014x over previous
//
#include <hip/hip_runtime.h>
#include <hip/hip_bf16.h>

#define N0_  320000
#define N1_  80000
#define N2_  16000
#define INC_ 128
#define HID_ 64
#define H1_  4
#define C1_  256   // H1*HID
#define OUT_ 48
#define OUTP_ 64   // padded layer-2 feature stride
#define NEG_ 0.2f

typedef __attribute__((ext_vector_type(8))) short bfrag8;   // 8 bf16 (4 VGPRs)
typedef __attribute__((ext_vector_type(4))) float ffrag4;   // 4 fp32 acc

__device__ __forceinline__ float bf2f(unsigned short u){
  unsigned int v = ((unsigned int)u) << 16;
  return __uint_as_float(v);
}
__device__ __forceinline__ unsigned short f2bf(float f){
  unsigned int u = __float_as_uint(f);
  u += 0x7FFFu + ((u >> 16) & 1u);   // round-to-nearest-even
  return (unsigned short)(u >> 16);
}
__device__ __forceinline__ void unpack2(unsigned int u, float& lo, float& hi){
  lo = __uint_as_float(u << 16);
  hi = __uint_as_float(u & 0xffff0000u);
}

// ---- all 4 weight transposes in one kernel (f32 [K][N] -> bf16 [N][K]) ----
__global__ void transpose_all(const float* __restrict__ Wl1, const float* __restrict__ Wr1,
                              const float* __restrict__ Wl2, const float* __restrict__ Wr2,
                              unsigned short* __restrict__ Wt1l, unsigned short* __restrict__ Wt1r,
                              unsigned short* __restrict__ Wt2l, unsigned short* __restrict__ Wt2r){
  int idx = blockIdx.x*256 + threadIdx.x;
  if (idx < 32768){ int n = idx >> 7, k = idx & 127; Wt1l[idx] = f2bf(Wl1[k*C1_ + n]); }
  else if (idx < 65536){ int j = idx - 32768; int n = j >> 7, k = j & 127; Wt1r[j] = f2bf(Wr1[k*C1_ + n]); }
  else if (idx < 77824){ int j = idx - 65536; int n = j >> 8, k = j & 255; Wt2l[j] = f2bf(Wl2[k*OUT_ + n]); }
  else if (idx < 90112){ int j = idx - 77824; int n = j >> 8, k = j & 255; Wt2r[j] = f2bf(Wr2[k*OUT_ + n]); }
}

// ------- fused GEMM1 (R0/R4-exact, 107.5us measured): stage A once; 2 passes -------
// JOURNAL — PINNED after 4 failed restructures; do not touch without new counter evidence:
//  R1: launch_bounds(256,4) reg cap 128 < acc(64)+bfr(64)+addr -> spills, +50MB, 133us.
//  R2: +pf[8] f32 next-tile prefetch at (256,3) -> spills, +30MB, 124.6us.
//  R3: 512thr/8wave acc[2][4] + per-ks B reloads: no spills, Occ 42%, but ILP broken
//      (serial L2-load->MFMA chain) -> 148us. Occupancy is not the constraint; ILP is.
//  R5: operand-swapped C^T direct stores (no Cs): 32B scattered row segments ->
//      partial-sector WRITE-ALLOCATE RMW: FETCH +58MB, WRITE +115MB, 173us.
//      The Cs bounce's full 512B/wave row stores are LOAD-BEARING.
__global__ __launch_bounds__(256, 3) void gemm1_fused(
    const float* __restrict__ X,
    const unsigned short* __restrict__ Wtl, const unsigned short* __restrict__ Wtr,
    const float* __restrict__ bl, const float* __restrict__ br,
    unsigned short* __restrict__ outl, unsigned short* __restrict__ outr)
{
  __shared__ unsigned short As[64][136];   // +8 pad: 2-way bank aliasing only (free)
  __shared__ unsigned short Cs[64][264];   // epilogue bounce for coalesced stores
  const int t = threadIdx.x;
  const int lane = t & 63, wave = t >> 6;
  const int row0 = blockIdx.x << 6;
  const int l15 = lane & 15, q = lane >> 4;
  const int wcol = wave << 6;
  const int c4 = t & 31;

  #pragma unroll
  for (int i = 0; i < 8; ++i){
    int r = (i<<3) + (t>>5);
    float4 xv = *(const float4*)(X + ((size_t)(row0 + r) << 7) + (c4<<2));
    ushort4 s; s.x=f2bf(xv.x); s.y=f2bf(xv.y); s.z=f2bf(xv.z); s.w=f2bf(xv.w);
    *(ushort4*)(&As[r][c4<<2]) = s;
  }
  __syncthreads();

  const int npass = (row0 < N1_) ? 2 : 1;
  for (int pass = 0; pass < npass; ++pass){
    const unsigned short* Wt = pass ? Wtr : Wtl;
    const float* bias = pass ? br : bl;
    unsigned short* out = pass ? outr : outl;

    bfrag8 bfr[4][4];
    #pragma unroll
    for (int nt = 0; nt < 4; ++nt)
      #pragma unroll
      for (int ks = 0; ks < 4; ++ks)
        bfr[nt][ks] = *(const bfrag8*)(Wt + (size_t)(wcol + (nt<<4) + l15)*128 + (ks<<5) + (q<<3));

    ffrag4 z = {0.f, 0.f, 0.f, 0.f};
    ffrag4 acc[4][4];
    #pragma unroll
    for (int mt = 0; mt < 4; ++mt)
      #pragma unroll
      for (int nt = 0; nt < 4; ++nt) acc[mt][nt] = z;

    #pragma unroll
    for (int mt = 0; mt < 4; ++mt){
      #pragma unroll
      for (int ks = 0; ks < 4; ++ks){
        bfrag8 af = *(const bfrag8*)(&As[(mt<<4) + l15][(ks<<5) + (q<<3)]);
        #pragma unroll
        for (int nt = 0; nt < 4; ++nt)
          acc[mt][nt] = __builtin_amdgcn_mfma_f32_16x16x32_bf16(af, bfr[nt][ks], acc[mt][nt], 0, 0, 0);
      }
    }

    float bb[4];
    #pragma unroll
    for (int nt = 0; nt < 4; ++nt) bb[nt] = bias[wcol + (nt<<4) + l15];
    #pragma unroll
    for (int mt = 0; mt < 4; ++mt)
      #pragma unroll
      for (int nt = 0; nt < 4; ++nt)
        #pragma unroll
        for (int rg = 0; rg < 4; ++rg)
          Cs[(mt<<4) + (q<<2) + rg][wcol + (nt<<4) + l15] = f2bf(acc[mt][nt][rg] + bb[nt]);
    __syncthreads();
    #pragma unroll
    for (int i = 0; i < 8; ++i){
      int r = (i<<3) + (t>>5);
      *(bfrag8*)(out + ((size_t)(row0 + r) << 8) + (c4<<3)) = *(const bfrag8*)(&Cs[r][c4<<3]);
    }
    if (pass + 1 < npass) __syncthreads();   // protect Cs reuse
  }
}

// ------- fused GEMM2: [M,256] bf16 @ Wt2[48][256] + b -> f32 [M][64] zero-padded -------
__global__ __launch_bounds__(256) void gemm2_fused(
    const unsigned short* __restrict__ Hin,
    const unsigned short* __restrict__ Wtl, const unsigned short* __restrict__ Wtr,
    const float* __restrict__ bl, const float* __restrict__ br,
    float* __restrict__ outl, float* __restrict__ outr)
{
  __shared__ unsigned short As2[64][264];
  __shared__ unsigned short Bs2[48][264];
  const int t = threadIdx.x;
  const int lane = t & 63, wave = t >> 6;
  const int row0 = blockIdx.x << 6;
  const int l15 = lane & 15, q = lane >> 4;
  const int c32 = t & 31;

  #pragma unroll
  for (int i = 0; i < 8; ++i){
    int r = (i<<3) + (t>>5);
    *(bfrag8*)(&As2[r][c32<<3]) = *(const bfrag8*)(Hin + ((size_t)(row0 + r) << 8) + (c32<<3));
  }

  const int npass = (row0 < N2_) ? 2 : 1;
  for (int pass = 0; pass < npass; ++pass){
    const unsigned short* Wt = pass ? Wtr : Wtl;
    const float* bias = pass ? br : bl;
    float* out = pass ? outr : outl;

    if (pass) __syncthreads();          // prior mfma done before Bs2 overwrite
    #pragma unroll
    for (int i = 0; i < 6; ++i){
      int idx = i*256 + t;
      int r = idx >> 5, c = (idx & 31) << 3;
      *(bfrag8*)(&Bs2[r][c]) = *(const bfrag8*)(Wt + (size_t)r*256 + c);
    }
    __syncthreads();                    // also covers As2 staging on pass 0

    ffrag4 z = {0.f, 0.f, 0.f, 0.f};
    ffrag4 acc[3] = {z, z, z};
    #pragma unroll
    for (int ks = 0; ks < 8; ++ks){
      bfrag8 af = *(const bfrag8*)(&As2[(wave<<4) + l15][(ks<<5) + (q<<3)]);
      #pragma unroll
      for (int nt = 0; nt < 3; ++nt){
        bfrag8 bf = *(const bfrag8*)(&Bs2[(nt<<4) + l15][(ks<<5) + (q<<3)]);
        acc[nt] = __builtin_amdgcn_mfma_f32_16x16x32_bf16(af, bf, acc[nt], 0, 0, 0);
      }
    }
    #pragma unroll
    for (int nt = 0; nt < 3; ++nt){
      int col = (nt<<4) + l15;
      float bb = bias[col];
      #pragma unroll
      for (int rg = 0; rg < 4; ++rg){
        int row = row0 + (wave<<4) + (q<<2) + rg;
        out[(size_t)row*OUTP_ + col] = acc[nt][rg] + bb;
      }
    }
    #pragma unroll
    for (int rg = 0; rg < 4; ++rg){     // zero pad cols 48..63
      int row = row0 + (wave<<4) + (q<<2) + rg;
      out[(size_t)row*OUTP_ + 48 + l15] = 0.f;
    }
  }
}

// ---------------- CSR build: 3 kernels ----------------
__global__ void hist_both(const int* __restrict__ dst1, const int* __restrict__ dst2,
                          int* __restrict__ cnt1, int* __restrict__ cnt2, int E1, int E2){
  int i = blockIdx.x*256 + threadIdx.x;
  if (i < E1) atomicAdd(&cnt1[dst1[i]], 1);
  else if (i < E1 + E2) atomicAdd(&cnt2[dst2[i - E1]], 1);
}

__global__ __launch_bounds__(256) void scan_atomic_both(
    const int* __restrict__ cnt1, const int* __restrict__ cnt2,
    int* __restrict__ off1, int* __restrict__ off2,
    int* __restrict__ cur1, int* __restrict__ cur2,
    int* __restrict__ gpair, int n1, int n2, int nb1){
  __shared__ int s[256];
  __shared__ int base_s;
  const int* in; int* off; int* cur; int* g; int n; int b;
  if ((int)blockIdx.x < nb1){ in = cnt1; off = off1; cur = cur1; g = gpair;     n = n1; b = blockIdx.x; }
  else                      { in = cnt2; off = off2; cur = cur2; g = gpair + 1; n = n2; b = blockIdx.x - nb1; }
  int t = threadIdx.x, i = b*256 + t;
  int v = (i < n) ? in[i] : 0;
  s[t] = v; __syncthreads();
  #pragma unroll
  for (int d = 1; d < 256; d <<= 1){
    int u = (t >= d) ? s[t-d] : 0;
    __syncthreads();
    s[t] += u; __syncthreads();
  }
  if (t == 255) base_s = atomicAdd(g, s[255]);   // claim this block's range
  __syncthreads();
  if (i < n){
    int o = s[t] - v + base_s;
    off[i] = o; cur[i] = o;
  }
}

__global__ void scatter_both(const int* __restrict__ src1, const int* __restrict__ dst1,
                             const int* __restrict__ src2, const int* __restrict__ dst2,
                             int* __restrict__ cur1, int* __restrict__ cur2,
                             int* __restrict__ perm1, int* __restrict__ perm2, int E1, int E2){
  int i = blockIdx.x*256 + threadIdx.x;
  if (i < E1){
    int pos = atomicAdd(&cur1[dst1[i]], 1);
    perm1[pos] = src1[i];
  } else if (i < E1 + E2){
    int j = i - E1;
    int pos = atomicAdd(&cur2[dst2[j]], 1);
    perm2[pos] = src2[j];
  }
}

// ---------- fused layer-1 aggregation v3: 4 edges/iter, head-sliced full-line loads ----------
// JOURNAL:
//  v1 (~104us): 2 edges/iter, 32 lanes x 16B contiguous per row. Latency-bound
//     (VALU floor ~17us; 85% stall on L3 gather).
//  v2 FAILED (139us): 4 edges/iter but ebyte=sub<<5 -> each 16B load touches two
//     half-sectors of every 64B line (2x L2 transactions). Per-instruction footprint
//     must be dense full lines (load-side twin of the R5 store lesson).
//  v3: 4 edges in flight, lane owns chans [sub*8..+7] (head sub>>3) AND
//     [128+sub*8..+7] (head 2+(sub>>3)): each load instr = 4 rows x 256B contiguous.
//     Heads are independent -> separate pA/pB dots (xor 1,2,4) and denA/denB.
__global__ __launch_bounds__(256) void gat_aggregate1(
    const unsigned short* __restrict__ xl, const unsigned short* __restrict__ xr,
    const int* __restrict__ offsets, const int* __restrict__ counts,
    const int* __restrict__ perm, const float* __restrict__ att,
    const float* __restrict__ bias, unsigned short* __restrict__ hout, int n)
{
  int node = (blockIdx.x << 2) + (threadIdx.x >> 6);
  if (node >= n) return;
  const int lane = threadIdx.x & 63;
  const int slot = lane >> 4;          // edge index within quad (0..3)
  const int sub  = lane & 15;
  const int cA = sub << 3;             // channels cA..cA+7  (head sub>>3)
  const int cB = 128 + (sub << 3);     // channels cB..cB+7  (head 2+(sub>>3))
  const unsigned bA = (unsigned)cA << 1;   // byte offset in 512B row
  const unsigned bB = (unsigned)cB << 1;
  const char* xlb = (const char*)xl;

  const int st = offsets[node], cnt = counts[node];
  uint4 ruA = *(const uint4*)(xr + ((size_t)node << 8) + cA);
  uint4 ruB = *(const uint4*)(xr + ((size_t)node << 8) + cB);
  float rA[8], rB[8];
  unpack2(ruA.x, rA[0], rA[1]); unpack2(ruA.y, rA[2], rA[3]);
  unpack2(ruA.z, rA[4], rA[5]); unpack2(ruA.w, rA[6], rA[7]);
  unpack2(ruB.x, rB[0], rB[1]); unpack2(ruB.y, rB[2], rB[3]);
  unpack2(ruB.z, rB[4], rB[5]); unpack2(ruB.w, rB[6], rB[7]);
  float aA[8], aB[8];
  #pragma unroll
  for (int i = 0; i < 2; ++i){
    float4 avA = *(const float4*)(att + cA + (i<<2));
    float4 avB = *(const float4*)(att + cB + (i<<2));
    aA[4*i] = avA.x; aA[4*i+1] = avA.y; aA[4*i+2] = avA.z; aA[4*i+3] = avA.w;
    aB[4*i] = avB.x; aB[4*i+1] = avB.y; aB[4*i+2] = avB.z; aB[4*i+3] = avB.w;
  }

  float accA[8], accB[8];
  #pragma unroll
  for (int i = 0; i < 8; ++i){ accA[i] = 0.f; accB[i] = 0.f; }
  float denA = 0.f, denB = 0.f;

  for (int jb = 0; jb < cnt; jb += 64){
    int m = cnt - jb; if (m > 64) m = 64;
    int pv = (lane < m) ? perm[st + jb + lane] : 0;
    int s_cur = __shfl(pv, slot);
    uint4 xcA = *(const uint4*)(xlb + (((size_t)(unsigned)s_cur << 9) + bA));
    uint4 xcB = *(const uint4*)(xlb + (((size_t)(unsigned)s_cur << 9) + bB));
    for (int j = 0; j < m; j += 4){
      int s_next = __shfl(pv, (j + 4 + slot) & 63);   // out-of-range -> pv=0 lanes (safe)
      uint4 xnA = *(const uint4*)(xlb + (((size_t)(unsigned)s_next << 9) + bA));  // prefetch
      uint4 xnB = *(const uint4*)(xlb + (((size_t)(unsigned)s_next << 9) + bB));
      float xA[8], xB[8];
      unpack2(xcA.x, xA[0], xA[1]); unpack2(xcA.y, xA[2], xA[3]);
      unpack2(xcA.z, xA[4], xA[5]); unpack2(xcA.w, xA[6], xA[7]);
      unpack2(xcB.x, xB[0], xB[1]); unpack2(xcB.y, xB[2], xB[3]);
      unpack2(xcB.z, xB[4], xB[5]); unpack2(xcB.w, xB[6], xB[7]);
      float pA = 0.f, pB = 0.f;
      #pragma unroll
      for (int i = 0; i < 8; ++i){
        float vA = xA[i] + rA[i];
        float eA = fmaf(NEG_, fminf(vA, 0.f), fmaxf(vA, 0.f));
        pA = fmaf(eA, aA[i], pA);
        float vB = xB[i] + rB[i];
        float eB = fmaf(NEG_, fminf(vB, 0.f), fmaxf(vB, 0.f));
        pB = fmaf(eB, aB[i], pB);
      }
      pA += __shfl_xor(pA, 1); pA += __shfl_xor(pA, 2); pA += __shfl_xor(pA, 4);
      pB += __shfl_xor(pB, 1); pB += __shfl_xor(pB, 2); pB += __shfl_xor(pB, 4);
      float exA = __expf(pA);            // |alpha| bounded -> native exp safe
      float exB = __expf(pB);
      const bool live = (j + slot < m);
      exA = live ? exA : 0.f;
      exB = live ? exB : 0.f;
      denA += exA; denB += exB;
      #pragma unroll
      for (int i = 0; i < 8; ++i){
        accA[i] = fmaf(exA, xA[i], accA[i]);
        accB[i] = fmaf(exB, xB[i], accB[i]);
      }
      xcA = xnA; xcB = xnB;
    }
  }
  denA += __shfl_xor(denA, 16); denA += __shfl_xor(denA, 32);
  denB += __shfl_xor(denB, 16); denB += __shfl_xor(denB, 32);
  #pragma unroll
  for (int i = 0; i < 8; ++i){
    accA[i] += __shfl_xor(accA[i], 16); accA[i] += __shfl_xor(accA[i], 32);
    accB[i] += __shfl_xor(accB[i], 16); accB[i] += __shfl_xor(accB[i], 32);
  }

  if (slot == 0){
    float wA = 1.f / (denA + 1e-16f);
    float wB = 1.f / (denB + 1e-16f);
    float bAv[8], bBv[8];
    #pragma unroll
    for (int i = 0; i < 2; ++i){
      float4 b0 = *(const float4*)(bias + cA + (i<<2));
      float4 b1 = *(const float4*)(bias + cB + (i<<2));
      bAv[4*i] = b0.x; bAv[4*i+1] = b0.y; bAv[4*i+2] = b0.z; bAv[4*i+3] = b0.w;
      bBv[4*i] = b1.x; bBv[4*i+1] = b1.y; bBv[4*i+2] = b1.z; bBv[4*i+3] = b1.w;
    }
    unsigned int oA[4], oB[4];
    #pragma unroll
    for (int i = 0; i < 4; ++i){
      unsigned short loA = f2bf(fmaxf(fmaf(accA[2*i],   wA, bAv[2*i]),   0.f));
      unsigned short hiA = f2bf(fmaxf(fmaf(accA[2*i+1], wA, bAv[2*i+1]), 0.f));
      oA[i] = (unsigned)loA | ((unsigned)hiA << 16);
      unsigned short loB = f2bf(fmaxf(fmaf(accB[2*i],   wB, bBv[2*i]),   0.f));
      unsigned short hiB = f2bf(fmaxf(fmaf(accB[2*i+1], wB, bBv[2*i+1]), 0.f));
      oB[i] = (unsigned)loB | ((unsigned)hiB << 16);
    }
    *(uint4*)(hout + ((size_t)node << 8) + cA) = make_uint4(oA[0], oA[1], oA[2], oA[3]);
    *(uint4*)(hout + ((size_t)node << 8) + cB) = make_uint4(oB[0], oB[1], oB[2], oB[3]);
  }
}

// ---------- fused layer-2 aggregation + log_softmax: wave/node, 4 edges/iter, prefetch ----------
__global__ __launch_bounds__(256) void gat_aggregate2(
    const float* __restrict__ xl, const float* __restrict__ xr,   // padded [.,64]
    const int* __restrict__ offsets, const int* __restrict__ counts,
    const int* __restrict__ perm, const float* __restrict__ att,
    const float* __restrict__ bias, float* __restrict__ out, int n)
{
  int node = (blockIdx.x << 2) + (threadIdx.x >> 6);
  if (node >= n) return;
  const int lane = threadIdx.x & 63;
  const int slot = lane >> 4;          // 0..3
  const int sub  = lane & 15;          // 4 channels (pad beyond 48)
  const bool realc = sub < 12;

  const int st = offsets[node], cnt = counts[node];
  float4 r = *(const float4*)(xr + (size_t)node*OUTP_ + (sub<<2));   // pads are 0
  float4 a = realc ? *(const float4*)(att + (sub<<2)) : make_float4(0,0,0,0);
  float4 acc = make_float4(0,0,0,0);
  float den = 0.f;

  for (int jb = 0; jb < cnt; jb += 64){
    int m = cnt - jb; if (m > 64) m = 64;
    int pv = (lane < m) ? perm[st + jb + lane] : 0;
    int s_cur = __shfl(pv, slot);
    float4 xc = *(const float4*)(xl + (size_t)((unsigned)s_cur*OUTP_ + (sub<<2)));
    for (int j = 0; j < m; j += 4){
      int s_next = __shfl(pv, (j + 4 + slot) & 63);
      float4 xn = *(const float4*)(xl + (size_t)((unsigned)s_next*OUTP_ + (sub<<2)));
      float v0 = xc.x + r.x, v1 = xc.y + r.y, v2 = xc.z + r.z, v3 = xc.w + r.w;
      float p;
      p = fmaf(a.x, fmaf(NEG_, fminf(v0,0.f), fmaxf(v0,0.f)), 0.f);
      p = fmaf(a.y, fmaf(NEG_, fminf(v1,0.f), fmaxf(v1,0.f)), p);
      p = fmaf(a.z, fmaf(NEG_, fminf(v2,0.f), fmaxf(v2,0.f)), p);
      p = fmaf(a.w, fmaf(NEG_, fminf(v3,0.f), fmaxf(v3,0.f)), p);
      p += __shfl_xor(p, 1);
      p += __shfl_xor(p, 2);
      p += __shfl_xor(p, 4);
      p += __shfl_xor(p, 8);
      float ex = __expf(p);
      ex = (j + slot < m) ? ex : 0.f;
      den += ex;
      acc.x = fmaf(ex, xc.x, acc.x); acc.y = fmaf(ex, xc.y, acc.y);
      acc.z = fmaf(ex, xc.z, acc.z); acc.w = fmaf(ex, xc.w, acc.w);
      xc = xn;
    }
  }
  den += __shfl_xor(den, 16); den += __shfl_xor(den, 32);
  acc.x += __shfl_xor(acc.x, 16); acc.x += __shfl_xor(acc.x, 32);
  acc.y += __shfl_xor(acc.y, 16); acc.y += __shfl_xor(acc.y, 32);
  acc.z += __shfl_xor(acc.z, 16); acc.z += __shfl_xor(acc.z, 32);
  acc.w += __shfl_xor(acc.w, 16); acc.w += __shfl_xor(acc.w, 32);

  float w = 1.f / (den + 1e-16f);
  float4 b = realc ? *(const float4*)(bias + (sub<<2)) : make_float4(0,0,0,0);
  float v0 = fmaf(acc.x, w, b.x), v1 = fmaf(acc.y, w, b.y);
  float v2 = fmaf(acc.z, w, b.z), v3 = fmaf(acc.w, w, b.w);

  float mx = realc ? fmaxf(fmaxf(v0, v1), fmaxf(v2, v3)) : -3.0e38f;
  mx = fmaxf(mx, __shfl_xor(mx, 1)); mx = fmaxf(mx, __shfl_xor(mx, 2));
  mx = fmaxf(mx, __shfl_xor(mx, 4)); mx = fmaxf(mx, __shfl_xor(mx, 8));
  float es = realc ? (__expf(v0-mx) + __expf(v1-mx) + __expf(v2-mx) + __expf(v3-mx)) : 0.f;
  es += __shfl_xor(es, 1); es += __shfl_xor(es, 2);
  es += __shfl_xor(es, 4); es += __shfl_xor(es, 8);
  float ls = __logf(es);
  if (slot == 0 && realc){
    float4 o = make_float4(v0-mx-ls, v1-mx-ls, v2-mx-ls, v3-mx-ls);
    *(float4*)(out + (size_t)node*OUT_ + (sub<<2)) = o;
  }
}

extern "C" void kernel_launch(void* const* d_in, const int* in_sizes, int n_in,
                              void* d_out, int out_size, void* d_ws, size_t ws_size,
                              hipStream_t stream)
{
  const float* x    = (const float*)d_in[0];
  const float* Wl1  = (const float*)d_in[1];
  const float* bl1  = (const float*)d_in[2];
  const float* Wr1  = (const float*)d_in[3];
  const float* br1  = (const float*)d_in[4];
  const float* att1 = (const float*)d_in[5];
  const float* bias1= (const float*)d_in[6];
  const float* Wl2  = (const float*)d_in[7];
  const float* bl2  = (const float*)d_in[8];
  const float* Wr2  = (const float*)d_in[9];
  const float* br2  = (const float*)d_in[10];
  const float* att2 = (const float*)d_in[11];
  const float* bias2= (const float*)d_in[12];
  const int* src1 = (const int*)d_in[13];
  const int* dst1 = (const int*)d_in[14];
  const int* src2 = (const int*)d_in[15];
  const int* dst2 = (const int*)d_in[16];
  const int E1 = in_sizes[13];
  const int E2 = in_sizes[15];
  (void)n_in; (void)out_size; (void)ws_size;

  // ---- workspace layout (bytes), total ~275.5 MB ----
  char* ws = (char*)d_ws;
  unsigned short* xl1  = (unsigned short*)(ws + 0LL);          // bf16 [320000][256]
  unsigned short* xr1  = (unsigned short*)(ws + 163840000LL);  // bf16 [ 80000][256]
  unsigned short* hbuf = (unsigned short*)(ws + 204800000LL);  // bf16 [ 80000][256]
  float* xl2p   = (float*)(ws + 245760000LL);                  // f32  [ 80000][64] padded
  float* xr2p   = (float*)(ws + 266240000LL);                  // f32  [ 16000][64] padded
  int*   perm1  = (int*)  (ws + 270336000LL);                  // int  [800000]
  int*   perm2  = (int*)  (ws + 273536000LL);                  // int  [160000]
  int*   cnt1   = (int*)  (ws + 274176000LL);                  // int  [ 80000] (zeroed)
  int*   cnt2   = (int*)  (ws + 274496000LL);                  // int  [ 16000] (zeroed)
  int*   off1   = (int*)  (ws + 274560000LL);                  // int  [ 80000]
  int*   cur1   = (int*)  (ws + 274880000LL);                  // int  [ 80000]
  int*   off2   = (int*)  (ws + 275200000LL);                  // int  [ 16000]
  int*   cur2   = (int*)  (ws + 275264000LL);                  // int  [ 16000]
  int*   gpair  = (int*)  (ws + 275328000LL);                  // int  [     2] (zeroed)
  unsigned short* Wt1l = (unsigned short*)(ws + 275332096LL);  // bf16 [256][128]
  unsigned short* Wt1r = (unsigned short*)(ws + 275397632LL);  // bf16 [256][128]
  unsigned short* Wt2l = (unsigned short*)(ws + 275463168LL);  // bf16 [ 48][256]
  unsigned short* Wt2r = (unsigned short*)(ws + 275487744LL);  // bf16 [ 48][256]

  hipMemsetAsync(ws + 274176000LL, 0, 384000LL, stream);       // cnt1 + cnt2
  hipMemsetAsync(ws + 275328000LL, 0, 8LL, stream);            // gpair

  const int nb1 = (N1_ + 255) / 256;   // 313
  const int nb2 = (N2_ + 255) / 256;   // 63

  transpose_all<<<352, 256, 0, stream>>>(Wl1, Wr1, Wl2, Wr2, Wt1l, Wt1r, Wt2l, Wt2r);

  // CSR build for both edge sets
  hist_both       <<<(E1+E2+255)/256, 256, 0, stream>>>(dst1, dst2, cnt1, cnt2, E1, E2);
  scan_atomic_both<<<nb1+nb2, 256, 0, stream>>>(cnt1, cnt2, off1, off2, cur1, cur2,
                                                gpair, N1_, N2_, nb1);
  scatter_both    <<<(E1+E2+255)/256, 256, 0, stream>>>(src1, dst1, src2, dst2,
                                                        cur1, cur2, perm1, perm2, E1, E2);

  gemm1_fused<<<N0_/64, 256, 0, stream>>>(x, Wt1l, Wt1r, bl1, br1, xl1, xr1);

  gat_aggregate1<<<(N1_+3)/4, 256, 0, stream>>>(xl1, xr1, off1, cnt1, perm1,
                                                att1, bias1, hbuf, N1_);

  gemm2_fused<<<N1_/64, 256, 0, stream>>>(hbuf, Wt2l, Wt2r, bl2, br2, xl2p, xr2p);

  gat_aggregate2<<<(N2_+3)/4, 256, 0, stream>>>(xl2p, xr2p, off2, cnt2, perm2,
                                                att2, bias2, (float*)d_out, N2_);
}

// Round 8
// 538.793 us; speedup vs baseline: 1.0890x; 1.0630x over previous
//
#include <hip/hip_runtime.h>
#include <hip/hip_bf16.h>

#define N0_  320000
#define N1_  80000
#define N2_  16000
#define INC_ 128
#define HID_ 64
#define H1_  4
#define C1_  256   // H1*HID
#define OUT_ 48
#define OUTP_ 64   // padded layer-2 feature stride
#define NEG_ 0.2f

typedef __attribute__((ext_vector_type(8))) short bfrag8;   // 8 bf16 (4 VGPRs)
typedef __attribute__((ext_vector_type(4))) float ffrag4;   // 4 fp32 acc

__device__ __forceinline__ float bf2f(unsigned short u){
  unsigned int v = ((unsigned int)u) << 16;
  return __uint_as_float(v);
}
__device__ __forceinline__ unsigned short f2bf(float f){
  unsigned int u = __float_as_uint(f);
  u += 0x7FFFu + ((u >> 16) & 1u);   // round-to-nearest-even
  return (unsigned short)(u >> 16);
}
__device__ __forceinline__ void unpack2(unsigned int u, float& lo, float& hi){
  lo = __uint_as_float(u << 16);
  hi = __uint_as_float(u & 0xffff0000u);
}

// ---- all 4 weight transposes in one kernel (f32 [K][N] -> bf16 [N][K]) ----
__global__ void transpose_all(const float* __restrict__ Wl1, const float* __restrict__ Wr1,
                              const float* __restrict__ Wl2, const float* __restrict__ Wr2,
                              unsigned short* __restrict__ Wt1l, unsigned short* __restrict__ Wt1r,
                              unsigned short* __restrict__ Wt2l, unsigned short* __restrict__ Wt2r){
  int idx = blockIdx.x*256 + threadIdx.x;
  if (idx < 32768){ int n = idx >> 7, k = idx & 127; Wt1l[idx] = f2bf(Wl1[k*C1_ + n]); }
  else if (idx < 65536){ int j = idx - 32768; int n = j >> 7, k = j & 127; Wt1r[j] = f2bf(Wr1[k*C1_ + n]); }
  else if (idx < 77824){ int j = idx - 65536; int n = j >> 8, k = j & 255; Wt2l[j] = f2bf(Wl2[k*OUT_ + n]); }
  else if (idx < 90112){ int j = idx - 77824; int n = j >> 8, k = j & 255; Wt2r[j] = f2bf(Wr2[k*OUT_ + n]); }
}

// ------- fused GEMM1 (R0/R4-exact, 107.5us measured): stage A once; 2 passes -------
// JOURNAL — PINNED after 4 failed restructures; do not touch without new counter evidence:
//  R1: launch_bounds(256,4) reg cap 128 < acc(64)+bfr(64)+addr -> spills, +50MB, 133us.
//  R2: +pf[8] f32 next-tile prefetch at (256,3) -> spills, +30MB, 124.6us.
//  R3: 512thr/8wave acc[2][4] + per-ks B reloads: no spills, Occ 42%, but ILP broken
//      (serial L2-load->MFMA chain) -> 148us. Occupancy is not the constraint; ILP is.
//  R5: operand-swapped C^T direct stores (no Cs): 32B scattered row segments ->
//      partial-sector WRITE-ALLOCATE RMW: FETCH +58MB, WRITE +115MB, 173us.
//      The Cs bounce's full 512B/wave row stores are LOAD-BEARING.
__global__ __launch_bounds__(256, 3) void gemm1_fused(
    const float* __restrict__ X,
    const unsigned short* __restrict__ Wtl, const unsigned short* __restrict__ Wtr,
    const float* __restrict__ bl, const float* __restrict__ br,
    unsigned short* __restrict__ outl, unsigned short* __restrict__ outr)
{
  __shared__ unsigned short As[64][136];   // +8 pad: 2-way bank aliasing only (free)
  __shared__ unsigned short Cs[64][264];   // epilogue bounce for coalesced stores
  const int t = threadIdx.x;
  const int lane = t & 63, wave = t >> 6;
  const int row0 = blockIdx.x << 6;
  const int l15 = lane & 15, q = lane >> 4;
  const int wcol = wave << 6;
  const int c4 = t & 31;

  #pragma unroll
  for (int i = 0; i < 8; ++i){
    int r = (i<<3) + (t>>5);
    float4 xv = *(const float4*)(X + ((size_t)(row0 + r) << 7) + (c4<<2));
    ushort4 s; s.x=f2bf(xv.x); s.y=f2bf(xv.y); s.z=f2bf(xv.z); s.w=f2bf(xv.w);
    *(ushort4*)(&As[r][c4<<2]) = s;
  }
  __syncthreads();

  const int npass = (row0 < N1_) ? 2 : 1;
  for (int pass = 0; pass < npass; ++pass){
    const unsigned short* Wt = pass ? Wtr : Wtl;
    const float* bias = pass ? br : bl;
    unsigned short* out = pass ? outr : outl;

    bfrag8 bfr[4][4];
    #pragma unroll
    for (int nt = 0; nt < 4; ++nt)
      #pragma unroll
      for (int ks = 0; ks < 4; ++ks)
        bfr[nt][ks] = *(const bfrag8*)(Wt + (size_t)(wcol + (nt<<4) + l15)*128 + (ks<<5) + (q<<3));

    ffrag4 z = {0.f, 0.f, 0.f, 0.f};
    ffrag4 acc[4][4];
    #pragma unroll
    for (int mt = 0; mt < 4; ++mt)
      #pragma unroll
      for (int nt = 0; nt < 4; ++nt) acc[mt][nt] = z;

    #pragma unroll
    for (int mt = 0; mt < 4; ++mt){
      #pragma unroll
      for (int ks = 0; ks < 4; ++ks){
        bfrag8 af = *(const bfrag8*)(&As[(mt<<4) + l15][(ks<<5) + (q<<3)]);
        #pragma unroll
        for (int nt = 0; nt < 4; ++nt)
          acc[mt][nt] = __builtin_amdgcn_mfma_f32_16x16x32_bf16(af, bfr[nt][ks], acc[mt][nt], 0, 0, 0);
      }
    }

    float bb[4];
    #pragma unroll
    for (int nt = 0; nt < 4; ++nt) bb[nt] = bias[wcol + (nt<<4) + l15];
    #pragma unroll
    for (int mt = 0; mt < 4; ++mt)
      #pragma unroll
      for (int nt = 0; nt < 4; ++nt)
        #pragma unroll
        for (int rg = 0; rg < 4; ++rg)
          Cs[(mt<<4) + (q<<2) + rg][wcol + (nt<<4) + l15] = f2bf(acc[mt][nt][rg] + bb[nt]);
    __syncthreads();
    #pragma unroll
    for (int i = 0; i < 8; ++i){
      int r = (i<<3) + (t>>5);
      *(bfrag8*)(out + ((size_t)(row0 + r) << 8) + (c4<<3)) = *(const bfrag8*)(&Cs[r][c4<<3]);
    }
    if (pass + 1 < npass) __syncthreads();   // protect Cs reuse
  }
}

// ------- fused GEMM2: [M,256] bf16 @ Wt2[48][256] + b -> f32 [M][64] zero-padded -------
__global__ __launch_bounds__(256) void gemm2_fused(
    const unsigned short* __restrict__ Hin,
    const unsigned short* __restrict__ Wtl, const unsigned short* __restrict__ Wtr,
    const float* __restrict__ bl, const float* __restrict__ br,
    float* __restrict__ outl, float* __restrict__ outr)
{
  __shared__ unsigned short As2[64][264];
  __shared__ unsigned short Bs2[48][264];
  const int t = threadIdx.x;
  const int lane = t & 63, wave = t >> 6;
  const int row0 = blockIdx.x << 6;
  const int l15 = lane & 15, q = lane >> 4;
  const int c32 = t & 31;

  #pragma unroll
  for (int i = 0; i < 8; ++i){
    int r = (i<<3) + (t>>5);
    *(bfrag8*)(&As2[r][c32<<3]) = *(const bfrag8*)(Hin + ((size_t)(row0 + r) << 8) + (c32<<3));
  }

  const int npass = (row0 < N2_) ? 2 : 1;
  for (int pass = 0; pass < npass; ++pass){
    const unsigned short* Wt = pass ? Wtr : Wtl;
    const float* bias = pass ? br : bl;
    float* out = pass ? outr : outl;

    if (pass) __syncthreads();          // prior mfma done before Bs2 overwrite
    #pragma unroll
    for (int i = 0; i < 6; ++i){
      int idx = i*256 + t;
      int r = idx >> 5, c = (idx & 31) << 3;
      *(bfrag8*)(&Bs2[r][c]) = *(const bfrag8*)(Wt + (size_t)r*256 + c);
    }
    __syncthreads();                    // also covers As2 staging on pass 0

    ffrag4 z = {0.f, 0.f, 0.f, 0.f};
    ffrag4 acc[3] = {z, z, z};
    #pragma unroll
    for (int ks = 0; ks < 8; ++ks){
      bfrag8 af = *(const bfrag8*)(&As2[(wave<<4) + l15][(ks<<5) + (q<<3)]);
      #pragma unroll
      for (int nt = 0; nt < 3; ++nt){
        bfrag8 bf = *(const bfrag8*)(&Bs2[(nt<<4) + l15][(ks<<5) + (q<<3)]);
        acc[nt] = __builtin_amdgcn_mfma_f32_16x16x32_bf16(af, bf, acc[nt], 0, 0, 0);
      }
    }
    #pragma unroll
    for (int nt = 0; nt < 3; ++nt){
      int col = (nt<<4) + l15;
      float bb = bias[col];
      #pragma unroll
      for (int rg = 0; rg < 4; ++rg){
        int row = row0 + (wave<<4) + (q<<2) + rg;
        out[(size_t)row*OUTP_ + col] = acc[nt][rg] + bb;
      }
    }
    #pragma unroll
    for (int rg = 0; rg < 4; ++rg){     // zero pad cols 48..63
      int row = row0 + (wave<<4) + (q<<2) + rg;
      out[(size_t)row*OUTP_ + 48 + l15] = 0.f;
    }
  }
}

// ---------------- CSR build: 3 kernels ----------------
__global__ void hist_both(const int* __restrict__ dst1, const int* __restrict__ dst2,
                          int* __restrict__ cnt1, int* __restrict__ cnt2, int E1, int E2){
  int i = blockIdx.x*256 + threadIdx.x;
  if (i < E1) atomicAdd(&cnt1[dst1[i]], 1);
  else if (i < E1 + E2) atomicAdd(&cnt2[dst2[i - E1]], 1);
}

__global__ __launch_bounds__(256) void scan_atomic_both(
    const int* __restrict__ cnt1, const int* __restrict__ cnt2,
    int* __restrict__ off1, int* __restrict__ off2,
    int* __restrict__ cur1, int* __restrict__ cur2,
    int* __restrict__ gpair, int n1, int n2, int nb1){
  __shared__ int s[256];
  __shared__ int base_s;
  const int* in; int* off; int* cur; int* g; int n; int b;
  if ((int)blockIdx.x < nb1){ in = cnt1; off = off1; cur = cur1; g = gpair;     n = n1; b = blockIdx.x; }
  else                      { in = cnt2; off = off2; cur = cur2; g = gpair + 1; n = n2; b = blockIdx.x - nb1; }
  int t = threadIdx.x, i = b*256 + t;
  int v = (i < n) ? in[i] : 0;
  s[t] = v; __syncthreads();
  #pragma unroll
  for (int d = 1; d < 256; d <<= 1){
    int u = (t >= d) ? s[t-d] : 0;
    __syncthreads();
    s[t] += u; __syncthreads();
  }
  if (t == 255) base_s = atomicAdd(g, s[255]);   // claim this block's range
  __syncthreads();
  if (i < n){
    int o = s[t] - v + base_s;
    off[i] = o; cur[i] = o;
  }
}

__global__ void scatter_both(const int* __restrict__ src1, const int* __restrict__ dst1,
                             const int* __restrict__ src2, const int* __restrict__ dst2,
                             int* __restrict__ cur1, int* __restrict__ cur2,
                             int* __restrict__ perm1, int* __restrict__ perm2, int E1, int E2){
  int i = blockIdx.x*256 + threadIdx.x;
  if (i < E1){
    int pos = atomicAdd(&cur1[dst1[i]], 1);
    perm1[pos] = src1[i];
  } else if (i < E1 + E2){
    int j = i - E1;
    int pos = atomicAdd(&cur2[dst2[j]], 1);
    perm2[pos] = src2[j];
  }
}

// ---------- fused layer-1 aggregation v4: v1-exact layout + 2-deep gather prefetch ----------
// JOURNAL:
//  v1 (<=107.5us, never in top-5): 2 edges/iter, 32 lanes x 16B = full 512B row/edge,
//     1024B dense per load instr, 1-ahead prefetch.
//  v2 FAILED (139us): 4 edges/iter, ebyte=sub<<5 half-line splits.
//  v3 FAILED (140us): 4 edges/iter, head-sliced FULL-line loads — SAME 140 as v2.
//     => line-density was NOT v2's problem; the 4-slot restructure itself regresses
//     (mechanism unresolved). Rule: only minimal deltas from the v1 shape.
//  v4: v1-exact + prefetch depth 1->2 iterations (xc,xn in flight; issue j+4 in loop).
//     +4 VGPRs. If still >=108: agg1 is issue/VALU-bound, not latency-bound ->
//     next card is packed-f32 math (float2 / v_pk_fma_f32).
__global__ __launch_bounds__(256) void gat_aggregate1(
    const unsigned short* __restrict__ xl, const unsigned short* __restrict__ xr,
    const int* __restrict__ offsets, const int* __restrict__ counts,
    const int* __restrict__ perm, const float* __restrict__ att,
    const float* __restrict__ bias, unsigned short* __restrict__ hout, int n)
{
  int node = (blockIdx.x << 2) + (threadIdx.x >> 6);
  if (node >= n) return;
  const int lane = threadIdx.x & 63;
  const int slot = lane >> 5;          // edge parity
  const int sub  = lane & 31;
  const int elem = sub << 3;           // 8 channels per lane (head = sub>>3)
  const unsigned int ebyte = (unsigned)elem << 1;
  const char* xlb = (const char*)xl;

  const int st = offsets[node], cnt = counts[node];
  uint4 ru = *(const uint4*)(xr + ((size_t)node << 8) + elem);
  float r[8];
  unpack2(ru.x, r[0], r[1]); unpack2(ru.y, r[2], r[3]);
  unpack2(ru.z, r[4], r[5]); unpack2(ru.w, r[6], r[7]);
  float4 al = *(const float4*)(att + elem);
  float4 ah = *(const float4*)(att + elem + 4);
  float a[8] = {al.x, al.y, al.z, al.w, ah.x, ah.y, ah.z, ah.w};

  float acc[8] = {0,0,0,0,0,0,0,0};
  float den = 0.f;

  for (int jb = 0; jb < cnt; jb += 64){
    int m = cnt - jb; if (m > 64) m = 64;
    int pv = (lane < m) ? perm[st + jb + lane] : 0;
    int s_cur = __shfl(pv, slot);
    uint4 xc = *(const uint4*)(xlb + (((unsigned)s_cur << 9) + ebyte));      // iter 0
    int s_nx = __shfl(pv, (2 + slot) & 63);
    uint4 xn = *(const uint4*)(xlb + (((unsigned)s_nx << 9) + ebyte));       // iter 1
    for (int j = 0; j < m; j += 2){
      int s_ff = __shfl(pv, (j + 4 + slot) & 63);    // out-of-range -> pv=0 lanes (safe)
      uint4 xf = *(const uint4*)(xlb + (((unsigned)s_ff << 9) + ebyte));     // iter j/2+2
      float x[8];
      unpack2(xc.x, x[0], x[1]); unpack2(xc.y, x[2], x[3]);
      unpack2(xc.z, x[4], x[5]); unpack2(xc.w, x[6], x[7]);
      float p = 0.f;
      #pragma unroll
      for (int i = 0; i < 8; ++i){
        float v = x[i] + r[i];
        float e = fmaf(NEG_, fminf(v, 0.f), fmaxf(v, 0.f));
        p = fmaf(e, a[i], p);
      }
      p += __shfl_xor(p, 1);
      p += __shfl_xor(p, 2);
      p += __shfl_xor(p, 4);         // full 64-ch head dot on all 8 lanes
      float ex = __expf(p);          // |alpha| bounded -> native exp safe
      ex = (j + slot < m) ? ex : 0.f;
      den += ex;
      #pragma unroll
      for (int i = 0; i < 8; ++i) acc[i] = fmaf(ex, x[i], acc[i]);
      xc = xn; xn = xf;
    }
  }
  den += __shfl_xor(den, 32);
  #pragma unroll
  for (int i = 0; i < 8; ++i) acc[i] += __shfl_xor(acc[i], 32);

  if (slot == 0){
    float w = 1.f / (den + 1e-16f);
    float4 bl = *(const float4*)(bias + elem);
    float4 bh = *(const float4*)(bias + elem + 4);
    float b[8] = {bl.x, bl.y, bl.z, bl.w, bh.x, bh.y, bh.z, bh.w};
    unsigned int o[4];
    #pragma unroll
    for (int i = 0; i < 4; ++i){
      unsigned short lo = f2bf(fmaxf(fmaf(acc[2*i],   w, b[2*i]),   0.f));
      unsigned short hi = f2bf(fmaxf(fmaf(acc[2*i+1], w, b[2*i+1]), 0.f));
      o[i] = (unsigned)lo | ((unsigned)hi << 16);
    }
    *(uint4*)(hout + ((size_t)node << 8) + elem) = make_uint4(o[0], o[1], o[2], o[3]);
  }
}

// ---------- fused layer-2 aggregation + log_softmax: wave/node, 4 edges/iter, prefetch ----------
__global__ __launch_bounds__(256) void gat_aggregate2(
    const float* __restrict__ xl, const float* __restrict__ xr,   // padded [.,64]
    const int* __restrict__ offsets, const int* __restrict__ counts,
    const int* __restrict__ perm, const float* __restrict__ att,
    const float* __restrict__ bias, float* __restrict__ out, int n)
{
  int node = (blockIdx.x << 2) + (threadIdx.x >> 6);
  if (node >= n) return;
  const int lane = threadIdx.x & 63;
  const int slot = lane >> 4;          // 0..3
  const int sub  = lane & 15;          // 4 channels (pad beyond 48)
  const bool realc = sub < 12;

  const int st = offsets[node], cnt = counts[node];
  float4 r = *(const float4*)(xr + (size_t)node*OUTP_ + (sub<<2));   // pads are 0
  float4 a = realc ? *(const float4*)(att + (sub<<2)) : make_float4(0,0,0,0);
  float4 acc = make_float4(0,0,0,0);
  float den = 0.f;

  for (int jb = 0; jb < cnt; jb += 64){
    int m = cnt - jb; if (m > 64) m = 64;
    int pv = (lane < m) ? perm[st + jb + lane] : 0;
    int s_cur = __shfl(pv, slot);
    float4 xc = *(const float4*)(xl + (size_t)((unsigned)s_cur*OUTP_ + (sub<<2)));
    for (int j = 0; j < m; j += 4){
      int s_next = __shfl(pv, (j + 4 + slot) & 63);
      float4 xn = *(const float4*)(xl + (size_t)((unsigned)s_next*OUTP_ + (sub<<2)));
      float v0 = xc.x + r.x, v1 = xc.y + r.y, v2 = xc.z + r.z, v3 = xc.w + r.w;
      float p;
      p = fmaf(a.x, fmaf(NEG_, fminf(v0,0.f), fmaxf(v0,0.f)), 0.f);
      p = fmaf(a.y, fmaf(NEG_, fminf(v1,0.f), fmaxf(v1,0.f)), p);
      p = fmaf(a.z, fmaf(NEG_, fminf(v2,0.f), fmaxf(v2,0.f)), p);
      p = fmaf(a.w, fmaf(NEG_, fminf(v3,0.f), fmaxf(v3,0.f)), p);
      p += __shfl_xor(p, 1);
      p += __shfl_xor(p, 2);
      p += __shfl_xor(p, 4);
      p += __shfl_xor(p, 8);
      float ex = __expf(p);
      ex = (j + slot < m) ? ex : 0.f;
      den += ex;
      acc.x = fmaf(ex, xc.x, acc.x); acc.y = fmaf(ex, xc.y, acc.y);
      acc.z = fmaf(ex, xc.z, acc.z); acc.w = fmaf(ex, xc.w, acc.w);
      xc = xn;
    }
  }
  den += __shfl_xor(den, 16); den += __shfl_xor(den, 32);
  acc.x += __shfl_xor(acc.x, 16); acc.x += __shfl_xor(acc.x, 32);
  acc.y += __shfl_xor(acc.y, 16); acc.y += __shfl_xor(acc.y, 32);
  acc.z += __shfl_xor(acc.z, 16); acc.z += __shfl_xor(acc.z, 32);
  acc.w += __shfl_xor(acc.w, 16); acc.w += __shfl_xor(acc.w, 32);

  float w = 1.f / (den + 1e-16f);
  float4 b = realc ? *(const float4*)(bias + (sub<<2)) : make_float4(0,0,0,0);
  float v0 = fmaf(acc.x, w, b.x), v1 = fmaf(acc.y, w, b.y);
  float v2 = fmaf(acc.z, w, b.z), v3 = fmaf(acc.w, w, b.w);

  float mx = realc ? fmaxf(fmaxf(v0, v1), fmaxf(v2, v3)) : -3.0e38f;
  mx = fmaxf(mx, __shfl_xor(mx, 1)); mx = fmaxf(mx, __shfl_xor(mx, 2));
  mx = fmaxf(mx, __shfl_xor(mx, 4)); mx = fmaxf(mx, __shfl_xor(mx, 8));
  float es = realc ? (__expf(v0-mx) + __expf(v1-mx) + __expf(v2-mx) + __expf(v3-mx)) : 0.f;
  es += __shfl_xor(es, 1); es += __shfl_xor(es, 2);
  es += __shfl_xor(es, 4); es += __shfl_xor(es, 8);
  float ls = __logf(es);
  if (slot == 0 && realc){
    float4 o = make_float4(v0-mx-ls, v1-mx-ls, v2-mx-ls, v3-mx-ls);
    *(float4*)(out + (size_t)node*OUT_ + (sub<<2)) = o;
  }
}

extern "C" void kernel_launch(void* const* d_in, const int* in_sizes, int n_in,
                              void* d_out, int out_size, void* d_ws, size_t ws_size,
                              hipStream_t stream)
{
  const float* x    = (const float*)d_in[0];
  const float* Wl1  = (const float*)d_in[1];
  const float* bl1  = (const float*)d_in[2];
  const float* Wr1  = (const float*)d_in[3];
  const float* br1  = (const float*)d_in[4];
  const float* att1 = (const float*)d_in[5];
  const float* bias1= (const float*)d_in[6];
  const float* Wl2  = (const float*)d_in[7];
  const float* bl2  = (const float*)d_in[8];
  const float* Wr2  = (const float*)d_in[9];
  const float* br2  = (const float*)d_in[10];
  const float* att2 = (const float*)d_in[11];
  const float* bias2= (const float*)d_in[12];
  const int* src1 = (const int*)d_in[13];
  const int* dst1 = (const int*)d_in[14];
  const int* src2 = (const int*)d_in[15];
  const int* dst2 = (const int*)d_in[16];
  const int E1 = in_sizes[13];
  const int E2 = in_sizes[15];
  (void)n_in; (void)out_size; (void)ws_size;

  // ---- workspace layout (bytes), total ~275.5 MB ----
  char* ws = (char*)d_ws;
  unsigned short* xl1  = (unsigned short*)(ws + 0LL);          // bf16 [320000][256]
  unsigned short* xr1  = (unsigned short*)(ws + 163840000LL);  // bf16 [ 80000][256]
  unsigned short* hbuf = (unsigned short*)(ws + 204800000LL);  // bf16 [ 80000][256]
  float* xl2p   = (float*)(ws + 245760000LL);                  // f32  [ 80000][64] padded
  float* xr2p   = (float*)(ws + 266240000LL);                  // f32  [ 16000][64] padded
  int*   perm1  = (int*)  (ws + 270336000LL);                  // int  [800000]
  int*   perm2  = (int*)  (ws + 273536000LL);                  // int  [160000]
  int*   cnt1   = (int*)  (ws + 274176000LL);                  // int  [ 80000] (zeroed)
  int*   cnt2   = (int*)  (ws + 274496000LL);                  // int  [ 16000] (zeroed)
  int*   off1   = (int*)  (ws + 274560000LL);                  // int  [ 80000]
  int*   cur1   = (int*)  (ws + 274880000LL);                  // int  [ 80000]
  int*   off2   = (int*)  (ws + 275200000LL);                  // int  [ 16000]
  int*   cur2   = (int*)  (ws + 275264000LL);                  // int  [ 16000]
  int*   gpair  = (int*)  (ws + 275328000LL);                  // int  [     2] (zeroed)
  unsigned short* Wt1l = (unsigned short*)(ws + 275332096LL);  // bf16 [256][128]
  unsigned short* Wt1r = (unsigned short*)(ws + 275397632LL);  // bf16 [256][128]
  unsigned short* Wt2l = (unsigned short*)(ws + 275463168LL);  // bf16 [ 48][256]
  unsigned short* Wt2r = (unsigned short*)(ws + 275487744LL);  // bf16 [ 48][256]

  hipMemsetAsync(ws + 274176000LL, 0, 384000LL, stream);       // cnt1 + cnt2
  hipMemsetAsync(ws + 275328000LL, 0, 8LL, stream);            // gpair

  const int nb1 = (N1_ + 255) / 256;   // 313
  const int nb2 = (N2_ + 255) / 256;   // 63

  transpose_all<<<352, 256, 0, stream>>>(Wl1, Wr1, Wl2, Wr2, Wt1l, Wt1r, Wt2l, Wt2r);

  // CSR build for both edge sets
  hist_both       <<<(E1+E2+255)/256, 256, 0, stream>>>(dst1, dst2, cnt1, cnt2, E1, E2);
  scan_atomic_both<<<nb1+nb2, 256, 0, stream>>>(cnt1, cnt2, off1, off2, cur1, cur2,
                                                gpair, N1_, N2_, nb1);
  scatter_both    <<<(E1+E2+255)/256, 256, 0, stream>>>(src1, dst1, src2, dst2,
                                                        cur1, cur2, perm1, perm2, E1, E2);

  gemm1_fused<<<N0_/64, 256, 0, stream>>>(x, Wt1l, Wt1r, bl1, br1, xl1, xr1);

  gat_aggregate1<<<(N1_+3)/4, 256, 0, stream>>>(xl1, xr1, off1, cnt1, perm1,
                                                att1, bias1, hbuf, N1_);

  gemm2_fused<<<N1_/64, 256, 0, stream>>>(hbuf, Wt2l, Wt2r, bl2, br2, xl2p, xr2p);

  gat_aggregate2<<<(N2_+3)/4, 256, 0, stream>>>(xl2p, xr2p, off2, cnt2, perm2,
                                                att2, bias2, (float*)d_out, N2_);
}